// Round 16
// baseline (1118.887 us; speedup 1.0000x reference)
//
#include <hip/hip_runtime.h>
#include <hip/hip_cooperative_groups.h>
namespace cg = cooperative_groups;

#define NN   3000
#define EE   48000
#define KK1  1500
#define KK2  750
#define KK2P 752      // padded row stride (float4 alignment)
#define HIDC 64
#define SLOT 64       // max raw in-degree slots (mean 16; Poisson tail safe)
#define ESPLIT 4      // e-split factor for level-2 augment

#define CAP0  64      // CSR0 row capacity
#define CAP1  768     // CSR1 row capacity
#define CAP2  768     // CSR2 row capacity (>=750: lossless)
#define CAPB0 64      // filtered-CSR capacity, level 0 -> 1
#define CAPMAX 768

// ================= shared device helpers (used by mega kernel) =================

// GCN aggregation phase: block-per-row grid-stride; 4 waves × 8-ILP; LDS reduce.
__device__ __forceinline__ void agg_phase(const int* __restrict__ cols, const float* __restrict__ vals,
                                          const int* __restrict__ cnt, int CAP,
                                          const float* __restrict__ g, const float* __restrict__ dinv,
                                          const float* __restrict__ bias, float* __restrict__ outp,
                                          int n, int C, int do_tanh,
                                          const float* __restrict__ p, float* __restrict__ score,
                                          float (*red)[64]) {
    int w = threadIdx.x >> 6, lane = threadIdx.x & 63;
    bool act = lane < C;
    for (int row = blockIdx.x; row < n; row += gridDim.x) {
        int nz = cnt[row];
        const int*   rc = cols + (size_t)row * CAP;
        const float* rv = vals + (size_t)row * CAP;
        float a0 = 0.f, a1 = 0.f, a2 = 0.f, a3 = 0.f;
        float a4 = 0.f, a5 = 0.f, a6 = 0.f, a7 = 0.f;
        for (int e = 8 * w; e + 8 <= nz; e += 32) {
            int   c0 = rc[e],     c1 = rc[e + 1], c2 = rc[e + 2], c3 = rc[e + 3];
            int   c4 = rc[e + 4], c5 = rc[e + 5], c6 = rc[e + 6], c7 = rc[e + 7];
            float v0 = rv[e],     v1 = rv[e + 1], v2 = rv[e + 2], v3 = rv[e + 3];
            float v4 = rv[e + 4], v5 = rv[e + 5], v6 = rv[e + 6], v7 = rv[e + 7];
            if (act) {
                a0 += v0 * g[(size_t)c0 * C + lane];
                a1 += v1 * g[(size_t)c1 * C + lane];
                a2 += v2 * g[(size_t)c2 * C + lane];
                a3 += v3 * g[(size_t)c3 * C + lane];
                a4 += v4 * g[(size_t)c4 * C + lane];
                a5 += v5 * g[(size_t)c5 * C + lane];
                a6 += v6 * g[(size_t)c6 * C + lane];
                a7 += v7 * g[(size_t)c7 * C + lane];
            }
        }
        if (w == 0) {
            for (int e = nz & ~7; e < nz; ++e)
                if (act) a0 += rv[e] * g[(size_t)rc[e] * C + lane];
        }
        __syncthreads();
        red[w][lane] = ((a0 + a1) + (a2 + a3)) + ((a4 + a5) + (a6 + a7));
        __syncthreads();
        if (w == 0) {
            float o = 0.f;
            if (act) {
                float a = (red[0][lane] + red[1][lane]) + (red[2][lane] + red[3][lane])
                        + 2.0f * g[(size_t)row * C + lane];
                o = dinv[row] * a + bias[lane];
                if (do_tanh) o = tanhf(o);
                outp[(size_t)row * C + lane] = o;
            }
            if (p) {
                float pv = p[lane];
                float d = o * pv, pp = pv * pv;
                for (int off = 32; off; off >>= 1) {
                    d  += __shfl_down(d, off, 64);
                    pp += __shfl_down(pp, off, 64);
                }
                if (lane == 0) score[row] = tanhf(d * rsqrtf(pp));
            }
        }
    }
}

// TopK + pool phase: block-per-candidate grid-stride; exact jax.lax.top_k order.
__device__ __forceinline__ void topk_phase(const float* __restrict__ score, const float* __restrict__ h,
                                           int n, int k, int* __restrict__ perm, int* __restrict__ selpos,
                                           float* __restrict__ hp, int* redi, int* srank) {
    int lane = threadIdx.x & 63, wid = threadIdx.x >> 6;
    for (int i = blockIdx.x; i < n; i += gridDim.x) {
        float si = score[i];
        int r = 0;
        for (int j = threadIdx.x; j < n; j += blockDim.x) {
            float sj = score[j];
            r += (sj > si) || (sj == si && j < i);
        }
        for (int off = 32; off; off >>= 1) r += __shfl_down(r, off, 64);
        __syncthreads();
        if (lane == 0) redi[wid] = r;
        __syncthreads();
        if (threadIdx.x == 0) {
            int rank = redi[0] + redi[1] + redi[2] + redi[3];
            *srank = rank;
            selpos[i] = (rank < k) ? rank : -1;
            if (rank < k) perm[rank] = i;
        }
        __syncthreads();
        int rank = *srank;
        if (rank < k && threadIdx.x < HIDC)
            hp[(size_t)rank * HIDC + threadIdx.x] = h[(size_t)i * HIDC + threadIdx.x] * si;
    }
}

// xw phase (wave-per-row): g[row,:] = dinv[row] * ((h[row,:] + up[selpos[row],:]) @ W)
__device__ __forceinline__ void xw_wave(const float* __restrict__ h, const float* __restrict__ up,
                                        const int* __restrict__ selpos,
                                        const float* __restrict__ W, const float* __restrict__ dinv,
                                        float* __restrict__ g, int n, int IC, int OC,
                                        int gw, int nwv) {
    int lane = threadIdx.x & 63;
    for (int row = gw; row < n; row += nwv) {
        int sp = selpos[row];
        float acc = 0.0f;
        for (int k = 0; k < IC; ++k) {
            float hv = h[(size_t)row * IC + k];
            if (sp >= 0) hv += up[(size_t)sp * IC + k];
            if (lane < OC) acc += hv * W[k * OC + lane];
        }
        if (lane < OC) g[(size_t)row * OC + lane] = dinv[row] * acc;
    }
}

// ================= mega kernel =================

struct MegaP {
    const float* x; const int* ei;
    const float* W0; const float* b0; const float* W1; const float* b1;
    const float* W2; const float* b2; const float* p1; const float* p2;
    const float* Wu0; const float* bu0; const float* Wu1; const float* bu1;
    float* out;
    int* slots; int* cntraw;
    int* cols0; float* vals0; int* cnt0;
    int* cols1; float* vals1; int* cnt1;
    int* cols2; float* vals2; int* cnt2;
    int* bc0C; float* bc0V; int* bc0N;
    float* Bcol2; float* T2p;
    float* g; float* res0; float* res1; float* hp; float* hp2; float* x2; float* xu;
    float* sc1; float* sc2; float* dinv0; float* dinv1; float* dinv2;
    int* perm1; int* perm2; int* selpos1; int* selpos2;
};

__global__ __launch_bounds__(256, 2) void k_mega(MegaP P) {
    cg::grid_group grid = cg::this_grid();
    __shared__ float srow[1504];
    __shared__ float ssum[4];
    __shared__ int   scol[CAPMAX];
    __shared__ float sval[CAPMAX];
    __shared__ float red[4][64];
    __shared__ int   redi[4];
    __shared__ int   srank;
    const int tid  = threadIdx.x;
    const int lane = tid & 63;
    const int w    = tid >> 6;
    const int gtid  = blockIdx.x * blockDim.x + tid;
    const int gsize = gridDim.x * blockDim.x;
    const int gw  = blockIdx.x * 4 + w;
    const int nwv = gridDim.x * 4;

    // P1: zero raw in-degree counters
    for (int i = gtid; i < NN; i += gsize) P.cntraw[i] = 0;
    grid.sync();

    // P2: per-edge slot scatter
    for (int e = gtid; e < EE; e += gsize) {
        int s = P.ei[e], t = P.ei[EE + e];
        int idx = atomicAdd(&P.cntraw[t], 1);
        if (idx < SLOT) P.slots[t * SLOT + idx] = s;
    }
    grid.sync();

    // P3: CSR0 sort+dedup + dinv0 + fused xw0
    for (int row = gw; row < NN; row += nwv) {
        int raw = P.cntraw[row];
        int nz = raw < SLOT ? raw : SLOT;
        int my = (lane < nz) ? P.slots[row * SLOT + lane] : 0x7FFFFFFF;
        int dup_before = 0, equal_total = 0;
        for (int f = 0; f < 64; ++f) {
            int cf = __shfl(my, f, 64);
            if (cf == my) { equal_total++; if (f < lane) dup_before++; }
        }
        bool leader = (lane < nz) && (dup_before == 0);
        unsigned long long lm = __ballot(leader);
        int dl = 0;
        unsigned long long m = lm;
        while (m) {
            int f = __builtin_ctzll(m); m &= m - 1;
            int cf = __shfl(my, f, 64);
            dl += (cf < my);
        }
        if (leader) {
            P.cols0[(size_t)row * CAP0 + dl] = my;
            P.vals0[(size_t)row * CAP0 + dl] = (float)equal_total;
        }
        float dv = rsqrtf((float)raw + 2.0f);
        if (lane == 0) { P.cnt0[row] = __popcll(lm); P.dinv0[row] = dv; }
        float acc = 0.0f;
#pragma unroll
        for (int k = 0; k < 16; ++k) acc += P.x[(size_t)row * 16 + k] * P.W0[k * 64 + lane];
        P.g[(size_t)row * 64 + lane] = dv * acc;
    }
    grid.sync();

    // P4: GCN0 aggregation -> res0 (+score sc1)
    agg_phase(P.cols0, P.vals0, P.cnt0, CAP0, P.g, P.dinv0, P.b0, P.res0, NN, 64, 1, P.p1, P.sc1, red);
    grid.sync();

    // P5: topk1 + pool -> perm1, selpos1, hp
    topk_phase(P.sc1, P.res0, NN, KK1, P.perm1, P.selpos1, P.hp, redi, &srank);
    grid.sync();

    // P6: filtered CSR of B0 restricted to selected columns
    for (int row = gw; row < NN; row += nwv) {
        int nz = P.cnt0[row];
        int base = 0;
        for (int e0 = 0; e0 < nz; e0 += 64) {
            int e = e0 + lane;
            int j = -1; float v = 0.0f;
            if (e < nz) {
                int c = P.cols0[(size_t)row * CAP0 + e];
                if (c != row) { j = P.selpos1[c]; v = P.vals0[(size_t)row * CAP0 + e]; }
            }
            unsigned long long mb = __ballot(j >= 0);
            if (j >= 0) {
                int idx = base + __popcll(mb & ((1ull << lane) - 1ull));
                if (idx < CAPB0) { P.bc0C[(size_t)row * CAPB0 + idx] = j; P.bc0V[(size_t)row * CAPB0 + idx] = v; }
            }
            base += __popcll(mb);
        }
        if (lane == 0) {
            int jd = P.selpos1[row];
            if (jd >= 0 && base < CAPB0) {
                P.bc0C[(size_t)row * CAPB0 + base] = jd;
                P.bc0V[(size_t)row * CAPB0 + base] = 1.0f;
                base++;
            }
            P.bc0N[row] = base < CAPB0 ? base : CAPB0;
        }
    }
    grid.sync();

    // P7: sparse augment level 0->1 (+fused xw1)
    for (int i = blockIdx.x; i < KK1; i += gridDim.x) {
        __syncthreads();                       // protect srow/ssum reuse across iterations
        int pi = P.perm1[i];
        int nzS = P.cnt0[pi];
        for (int t = tid; t < 1504; t += blockDim.x) srow[t] = 0.0f;
        __syncthreads();
        for (int ee = w; ee <= nzS; ee += 4) {
            int k; float kv;
            if (ee == nzS) { k = pi; kv = 1.0f; }
            else {
                k = P.cols0[(size_t)pi * CAP0 + ee];
                if (k == pi) continue;
                kv = P.vals0[(size_t)pi * CAP0 + ee];
            }
            int bn = P.bc0N[k];
            const int*   bc = P.bc0C + (size_t)k * CAPB0;
            const float* bv = P.bc0V + (size_t)k * CAPB0;
            for (int t = lane; t < bn; t += 64)
                atomicAdd(&srow[bc[t]], kv * bv[t]);
        }
        __syncthreads();
        if (tid == 0) srow[i] = 0.0f;
        __syncthreads();
        float psum = 0.0f;
        for (int t = tid; t < KK1; t += blockDim.x) psum += srow[t];
        for (int off = 32; off; off >>= 1) psum += __shfl_down(psum, off, 64);
        if (lane == 0) ssum[w] = psum;
        __syncthreads();
        if (w == 0) {
            if (lane == 0)
                P.dinv1[i] = rsqrtf((ssum[0] + ssum[1]) + (ssum[2] + ssum[3]) + 2.0f);
            int base = 0;
            for (int c0 = 0; c0 < KK1; c0 += 64) {
                int c = c0 + lane;
                float v = (c < KK1) ? srow[c] : 0.0f;
                unsigned long long mb = __ballot(v != 0.0f);
                if (v != 0.0f) {
                    int idx = base + __popcll(mb & ((1ull << lane) - 1ull));
                    if (idx < CAP1) {
                        P.cols1[(size_t)i * CAP1 + idx] = c;
                        P.vals1[(size_t)i * CAP1 + idx] = v;
                    }
                }
                base += __popcll(mb);
            }
            if (lane == 0) P.cnt1[i] = base < CAP1 ? base : CAP1;
        } else if (w == 1) {
            float dv = rsqrtf((ssum[0] + ssum[1]) + (ssum[2] + ssum[3]) + 2.0f);
            const float* hrow = P.hp + (size_t)i * 64;
            float acc = 0.0f;
            for (int k = 0; k < 64; ++k) acc += hrow[k] * P.W1[k * 64 + lane];
            P.g[(size_t)i * 64 + lane] = dv * acc;
        }
    }
    grid.sync();

    // P8: GCN1 aggregation -> res1 (+score sc2)
    agg_phase(P.cols1, P.vals1, P.cnt1, CAP1, P.g, P.dinv1, P.b1, P.res1, KK1, 64, 1, P.p2, P.sc2, red);
    grid.sync();

    // P9: topk2 + pool -> perm2, selpos2, hp2
    topk_phase(P.sc2, P.res1, KK1, KK2, P.perm2, P.selpos2, P.hp2, redi, &srank);
    grid.sync();

    // P10: dense Bcol2 panel (fused zero-fill + scatter)
    for (int row = blockIdx.x; row < KK1; row += gridDim.x) {
        float4* rowp = (float4*)(P.Bcol2 + (size_t)row * KK2P);
        float4 z = {0.f, 0.f, 0.f, 0.f};
        for (int q = tid; q < (KK2P >> 2); q += blockDim.x) rowp[q] = z;
        __syncthreads();
        int nz = P.cnt1[row];
        for (int e = tid; e < nz; e += blockDim.x) {
            int c = P.cols1[(size_t)row * CAP1 + e];
            if (c == row) continue;
            int j = P.selpos2[c];
            if (j >= 0) P.Bcol2[(size_t)row * KK2P + j] = P.vals1[(size_t)row * CAP1 + e];
        }
        if (tid == 0) {
            int j = P.selpos2[row];
            if (j >= 0) P.Bcol2[(size_t)row * KK2P + j] = 1.0f;
        }
        __syncthreads();                       // row fully built before next row reuses threads
    }
    grid.sync();

    // P11: level-2 augment e-split partials -> T2p
    for (int u = blockIdx.x; u < KK2 * ESPLIT; u += gridDim.x) {
        int i = u >> 2, sp = u & 3;
        int pi = P.perm2[i];
        int nz = P.cnt1[pi];
        __syncthreads();                       // protect scol/sval reuse
        for (int e = tid; e < nz; e += blockDim.x) {
            int c = P.cols1[(size_t)pi * CAP1 + e];
            scol[e] = c;
            sval[e] = (c == pi) ? 0.0f : P.vals1[(size_t)pi * CAP1 + e];
        }
        __syncthreads();
        int j0 = tid * 4;
        if (j0 < KK2P) {
            int j4 = j0 >> 2;
            float4 a = {0.f, 0.f, 0.f, 0.f};
            if (sp == 0) a = ((const float4*)(P.Bcol2 + (size_t)pi * KK2P))[j4];
            float4 acc1 = {0.f, 0.f, 0.f, 0.f};
            int e  = (nz * sp) / ESPLIT;
            int e1 = (nz * (sp + 1)) / ESPLIT;
            for (; e + 8 <= e1; e += 8) {
                float v0 = sval[e],     v1 = sval[e + 1], v2 = sval[e + 2], v3 = sval[e + 3];
                float v4 = sval[e + 4], v5 = sval[e + 5], v6 = sval[e + 6], v7 = sval[e + 7];
                float4 b0 = ((const float4*)(P.Bcol2 + (size_t)scol[e]     * KK2P))[j4];
                float4 b1 = ((const float4*)(P.Bcol2 + (size_t)scol[e + 1] * KK2P))[j4];
                float4 b2 = ((const float4*)(P.Bcol2 + (size_t)scol[e + 2] * KK2P))[j4];
                float4 b3 = ((const float4*)(P.Bcol2 + (size_t)scol[e + 3] * KK2P))[j4];
                float4 b4 = ((const float4*)(P.Bcol2 + (size_t)scol[e + 4] * KK2P))[j4];
                float4 b5 = ((const float4*)(P.Bcol2 + (size_t)scol[e + 5] * KK2P))[j4];
                float4 b6 = ((const float4*)(P.Bcol2 + (size_t)scol[e + 6] * KK2P))[j4];
                float4 b7 = ((const float4*)(P.Bcol2 + (size_t)scol[e + 7] * KK2P))[j4];
                a.x += v0 * b0.x + v1 * b1.x + v2 * b2.x + v3 * b3.x;
                a.y += v0 * b0.y + v1 * b1.y + v2 * b2.y + v3 * b3.y;
                a.z += v0 * b0.z + v1 * b1.z + v2 * b2.z + v3 * b3.z;
                a.w += v0 * b0.w + v1 * b1.w + v2 * b2.w + v3 * b3.w;
                acc1.x += v4 * b4.x + v5 * b5.x + v6 * b6.x + v7 * b7.x;
                acc1.y += v4 * b4.y + v5 * b5.y + v6 * b6.y + v7 * b7.y;
                acc1.z += v4 * b4.z + v5 * b5.z + v6 * b6.z + v7 * b7.z;
                acc1.w += v4 * b4.w + v5 * b5.w + v6 * b6.w + v7 * b7.w;
            }
            for (; e < e1; ++e) {
                float v = sval[e];
                float4 b = ((const float4*)(P.Bcol2 + (size_t)scol[e] * KK2P))[j4];
                a.x += v * b.x; a.y += v * b.y; a.z += v * b.z; a.w += v * b.w;
            }
            a.x += acc1.x; a.y += acc1.y; a.z += acc1.z; a.w += acc1.w;
            *(float4*)(P.T2p + ((size_t)sp * KK2 + i) * KK2P + j0) = a;
        }
    }
    grid.sync();

    // P12: sum partials -> CSR2 + dinv2 (+fused xw2)
    for (int row = gw; row < KK2; row += nwv) {
        const float* r0 = P.T2p + ((size_t)0 * KK2 + row) * KK2P;
        const float* r1 = P.T2p + ((size_t)1 * KK2 + row) * KK2P;
        const float* r2 = P.T2p + ((size_t)2 * KK2 + row) * KK2P;
        const float* r3 = P.T2p + ((size_t)3 * KK2 + row) * KK2P;
        int base = 0;
        float s = 0.0f;
        for (int c0 = 0; c0 < KK2; c0 += 64) {
            int c = c0 + lane;
            float v = 0.0f;
            if (c < KK2 && c != row) v = (r0[c] + r1[c]) + (r2[c] + r3[c]);
            unsigned long long mb = __ballot(v != 0.0f);
            if (v != 0.0f) {
                int idx = base + __popcll(mb & ((1ull << lane) - 1ull));
                if (idx < CAP2) {
                    P.cols2[(size_t)row * CAP2 + idx] = c;
                    P.vals2[(size_t)row * CAP2 + idx] = v;
                }
                s += v;
            }
            base += __popcll(mb);
        }
        for (int off = 32; off; off >>= 1) s += __shfl_xor(s, off, 64);
        float dv = rsqrtf(s + 2.0f);
        if (lane == 0) {
            P.cnt2[row] = base < CAP2 ? base : CAP2;
            P.dinv2[row] = dv;
        }
        const float* hrow = P.hp2 + (size_t)row * 64;
        float acc = 0.0f;
        for (int k = 0; k < 64; ++k) acc += hrow[k] * P.W2[k * 64 + lane];
        P.g[(size_t)row * 64 + lane] = dv * acc;
    }
    grid.sync();

    // P13: GCN2 aggregation -> x2
    agg_phase(P.cols2, P.vals2, P.cnt2, CAP2, P.g, P.dinv2, P.b2, P.x2, KK2, 64, 1, nullptr, nullptr, red);
    grid.sync();

    // P14: xw up-level-1: g = dinv1 * ((res1 + up(x2)) @ Wu0)
    xw_wave(P.res1, P.x2, P.selpos2, P.Wu0, P.dinv1, P.g, KK1, 64, 64, gw, nwv);
    grid.sync();

    // P15: GCN up-1 aggregation -> xu
    agg_phase(P.cols1, P.vals1, P.cnt1, CAP1, P.g, P.dinv1, P.bu0, P.xu, KK1, 64, 1, nullptr, nullptr, red);
    grid.sync();

    // P16: xw up-level-0: g = dinv0 * ((res0 + up(xu)) @ Wu1)  (OC=16)
    xw_wave(P.res0, P.xu, P.selpos1, P.Wu1, P.dinv0, P.g, NN, 64, 16, gw, nwv);
    grid.sync();

    // P17: GCN up-0 aggregation -> out (C=16, no tanh)
    agg_phase(P.cols0, P.vals0, P.cnt0, CAP0, P.g, P.dinv0, P.bu1, P.out, NN, 16, 0, nullptr, nullptr, red);
}

// ================= fallback kernels (r15-proven path) =================

__global__ void k_zero_i32(int* __restrict__ p, int n) {
    int i = blockIdx.x * blockDim.x + threadIdx.x;
    if (i < n) p[i] = 0;
}

__global__ void k_edge_slots(const int* __restrict__ ei, int* __restrict__ cntraw,
                             int* __restrict__ slots) {
    int e = blockIdx.x * blockDim.x + threadIdx.x;
    if (e >= EE) return;
    int s = ei[e];
    int t = ei[EE + e];
    int idx = atomicAdd(&cntraw[t], 1);
    if (idx < SLOT) slots[t * SLOT + idx] = s;
}

__global__ void k_csr0_sort(const int* __restrict__ cntraw, const int* __restrict__ slots,
                            int* __restrict__ cols, float* __restrict__ vals,
                            int* __restrict__ cnt, float* __restrict__ dinv,
                            const float* __restrict__ x, const float* __restrict__ W0,
                            float* __restrict__ g) {
    int row = blockIdx.x * (blockDim.x >> 6) + (threadIdx.x >> 6);
    int lane = threadIdx.x & 63;
    int raw = cntraw[row];
    int nz = raw < SLOT ? raw : SLOT;
    int my = (lane < nz) ? slots[row * SLOT + lane] : 0x7FFFFFFF;
    int dup_before = 0, equal_total = 0;
    for (int f = 0; f < 64; ++f) {
        int cf = __shfl(my, f, 64);
        if (cf == my) { equal_total++; if (f < lane) dup_before++; }
    }
    bool leader = (lane < nz) && (dup_before == 0);
    unsigned long long lm = __ballot(leader);
    int dl = 0;
    unsigned long long m = lm;
    while (m) {
        int f = __builtin_ctzll(m); m &= m - 1;
        int cf = __shfl(my, f, 64);
        dl += (cf < my);
    }
    if (leader) {
        cols[(size_t)row * CAP0 + dl] = my;
        vals[(size_t)row * CAP0 + dl] = (float)equal_total;
    }
    float dv = rsqrtf((float)raw + 2.0f);
    if (lane == 0) { cnt[row] = __popcll(lm); dinv[row] = dv; }
    float acc = 0.0f;
#pragma unroll
    for (int k = 0; k < 16; ++k) acc += x[(size_t)row * 16 + k] * W0[k * 64 + lane];
    g[(size_t)row * 64 + lane] = dv * acc;
}

__global__ void k_xw_scale(const float* __restrict__ h, const float* __restrict__ up,
                           const int* __restrict__ selpos,
                           const float* __restrict__ W, const float* __restrict__ dinv,
                           float* __restrict__ g, int n, int IC, int OC) {
    int row = blockIdx.x;
    int c = threadIdx.x;
    __shared__ float hr[64];
    if (c < IC) {
        float v = h[(size_t)row * IC + c];
        if (selpos) {
            int sp = selpos[row];
            if (sp >= 0) v += up[(size_t)sp * IC + c];
        }
        hr[c] = v;
    }
    __syncthreads();
    if (c >= OC) return;
    float acc = 0.0f;
    for (int k = 0; k < IC; ++k) acc += hr[k] * W[k * OC + c];
    g[(size_t)row * OC + c] = dinv[row] * acc;
}

__global__ void k_gcn_agg_csr(const int* __restrict__ cols, const float* __restrict__ vals,
                              const int* __restrict__ cnt, int CAP,
                              const float* __restrict__ g, const float* __restrict__ dinv,
                              const float* __restrict__ bias, float* __restrict__ out,
                              int n, int C, int do_tanh,
                              const float* __restrict__ p, float* __restrict__ score) {
    int row = blockIdx.x;
    int w = threadIdx.x >> 6;
    int lane = threadIdx.x & 63;
    int nz = cnt[row];
    const int*   rc = cols + (size_t)row * CAP;
    const float* rv = vals + (size_t)row * CAP;
    bool act = lane < C;
    float a0 = 0.f, a1 = 0.f, a2 = 0.f, a3 = 0.f;
    float a4 = 0.f, a5 = 0.f, a6 = 0.f, a7 = 0.f;
    for (int e = 8 * w; e + 8 <= nz; e += 32) {
        int   c0 = rc[e],     c1 = rc[e + 1], c2 = rc[e + 2], c3 = rc[e + 3];
        int   c4 = rc[e + 4], c5 = rc[e + 5], c6 = rc[e + 6], c7 = rc[e + 7];
        float v0 = rv[e],     v1 = rv[e + 1], v2 = rv[e + 2], v3 = rv[e + 3];
        float v4 = rv[e + 4], v5 = rv[e + 5], v6 = rv[e + 6], v7 = rv[e + 7];
        if (act) {
            a0 += v0 * g[(size_t)c0 * C + lane];
            a1 += v1 * g[(size_t)c1 * C + lane];
            a2 += v2 * g[(size_t)c2 * C + lane];
            a3 += v3 * g[(size_t)c3 * C + lane];
            a4 += v4 * g[(size_t)c4 * C + lane];
            a5 += v5 * g[(size_t)c5 * C + lane];
            a6 += v6 * g[(size_t)c6 * C + lane];
            a7 += v7 * g[(size_t)c7 * C + lane];
        }
    }
    if (w == 0) {
        for (int e = nz & ~7; e < nz; ++e)
            if (act) a0 += rv[e] * g[(size_t)rc[e] * C + lane];
    }
    __shared__ float red[4][64];
    red[w][lane] = ((a0 + a1) + (a2 + a3)) + ((a4 + a5) + (a6 + a7));
    __syncthreads();
    if (w == 0) {
        float o = 0.f;
        if (act) {
            float a = (red[0][lane] + red[1][lane]) + (red[2][lane] + red[3][lane])
                    + 2.0f * g[(size_t)row * C + lane];
            o = dinv[row] * a + bias[lane];
            if (do_tanh) o = tanhf(o);
            out[(size_t)row * C + lane] = o;
        }
        if (p) {
            float pv = p[lane];
            float d = o * pv, pp = pv * pv;
            for (int off = 32; off; off >>= 1) {
                d  += __shfl_down(d, off, 64);
                pp += __shfl_down(pp, off, 64);
            }
            if (lane == 0) score[row] = tanhf(d * rsqrtf(pp));
        }
    }
}

__global__ void k_topk(const float* __restrict__ score, const float* __restrict__ h,
                       int n, int k, int* __restrict__ perm, int* __restrict__ selpos,
                       float* __restrict__ hp) {
    int i = blockIdx.x;
    float si = score[i];
    int r = 0;
    for (int j = threadIdx.x; j < n; j += blockDim.x) {
        float sj = score[j];
        r += (sj > si) || (sj == si && j < i);
    }
    int lane = threadIdx.x & 63, wid = threadIdx.x >> 6;
    for (int off = 32; off; off >>= 1) r += __shfl_down(r, off, 64);
    __shared__ int red[4];
    __shared__ int srank;
    if (lane == 0) red[wid] = r;
    __syncthreads();
    if (threadIdx.x == 0) {
        int rank = red[0] + red[1] + red[2] + red[3];
        srank = rank;
        selpos[i] = (rank < k) ? rank : -1;
        if (rank < k) perm[rank] = i;
    }
    __syncthreads();
    int rank = srank;
    if (rank < k && threadIdx.x < HIDC)
        hp[(size_t)rank * HIDC + threadIdx.x] = h[(size_t)i * HIDC + threadIdx.x] * si;
}

__global__ void k_bcolcsr(const int* __restrict__ cols, const float* __restrict__ vals,
                          const int* __restrict__ cnt, int CAPS,
                          const int* __restrict__ selpos, int n,
                          int* __restrict__ bcC, float* __restrict__ bcV,
                          int* __restrict__ bcN, int CAPB) {
    int row = blockIdx.x * (blockDim.x >> 6) + (threadIdx.x >> 6);
    int lane = threadIdx.x & 63;
    if (row >= n) return;
    int nz = cnt[row];
    int base = 0;
    for (int e0 = 0; e0 < nz; e0 += 64) {
        int e = e0 + lane;
        int j = -1; float v = 0.0f;
        if (e < nz) {
            int c = cols[(size_t)row * CAPS + e];
            if (c != row) { j = selpos[c]; v = vals[(size_t)row * CAPS + e]; }
        }
        unsigned long long mb = __ballot(j >= 0);
        if (j >= 0) {
            int idx = base + __popcll(mb & ((1ull << lane) - 1ull));
            if (idx < CAPB) { bcC[(size_t)row * CAPB + idx] = j; bcV[(size_t)row * CAPB + idx] = v; }
        }
        base += __popcll(mb);
    }
    if (lane == 0) {
        int jd = selpos[row];
        if (jd >= 0 && base < CAPB) {
            bcC[(size_t)row * CAPB + base] = jd;
            bcV[(size_t)row * CAPB + base] = 1.0f;
            base++;
        }
        bcN[row] = base < CAPB ? base : CAPB;
    }
}

__global__ void k_aug_sparse(const int* __restrict__ perm,
                             const int* __restrict__ colsS, const float* __restrict__ valsS,
                             const int* __restrict__ cntS, int CAPS,
                             const int* __restrict__ bcC, const float* __restrict__ bcV,
                             const int* __restrict__ bcN, int CAPB, int kk,
                             int* __restrict__ colsD, float* __restrict__ valsD,
                             int* __restrict__ cntD, float* __restrict__ dinvD, int CAPD,
                             const float* __restrict__ hp, const float* __restrict__ W,
                             float* __restrict__ gOut) {
    __shared__ float srow[1504];
    __shared__ float ssum[4];
    int i = blockIdx.x;
    int pi = perm[i];
    int nzS = cntS[pi];
    for (int t = threadIdx.x; t < 1504; t += blockDim.x) srow[t] = 0.0f;
    __syncthreads();
    int w = threadIdx.x >> 6, lane = threadIdx.x & 63;
    for (int ee = w; ee <= nzS; ee += 4) {
        int k; float kv;
        if (ee == nzS) { k = pi; kv = 1.0f; }
        else {
            k = colsS[(size_t)pi * CAPS + ee];
            if (k == pi) continue;
            kv = valsS[(size_t)pi * CAPS + ee];
        }
        int bn = bcN[k];
        const int*   bc = bcC + (size_t)k * CAPB;
        const float* bv = bcV + (size_t)k * CAPB;
        for (int t = lane; t < bn; t += 64)
            atomicAdd(&srow[bc[t]], kv * bv[t]);
    }
    __syncthreads();
    if (threadIdx.x == 0) srow[i] = 0.0f;
    __syncthreads();
    float psum = 0.0f;
    for (int t = threadIdx.x; t < kk; t += blockDim.x) psum += srow[t];
    for (int off = 32; off; off >>= 1) psum += __shfl_down(psum, off, 64);
    if (lane == 0) ssum[w] = psum;
    __syncthreads();
    if (w == 0) {
        if (lane == 0)
            dinvD[i] = rsqrtf((ssum[0] + ssum[1]) + (ssum[2] + ssum[3]) + 2.0f);
        int base = 0;
        for (int c0 = 0; c0 < kk; c0 += 64) {
            int c = c0 + lane;
            float v = (c < kk) ? srow[c] : 0.0f;
            unsigned long long mb = __ballot(v != 0.0f);
            if (v != 0.0f) {
                int idx = base + __popcll(mb & ((1ull << lane) - 1ull));
                if (idx < CAPD) {
                    colsD[(size_t)i * CAPD + idx] = c;
                    valsD[(size_t)i * CAPD + idx] = v;
                }
            }
            base += __popcll(mb);
        }
        if (lane == 0) cntD[i] = base < CAPD ? base : CAPD;
    } else if (w == 1) {
        float dv = rsqrtf((ssum[0] + ssum[1]) + (ssum[2] + ssum[3]) + 2.0f);
        const float* hrow = hp + (size_t)i * 64;
        float acc = 0.0f;
        for (int k = 0; k < 64; ++k) acc += hrow[k] * W[k * 64 + lane];
        gOut[(size_t)i * 64 + lane] = dv * acc;
    }
}

__global__ void k_bcol_scatter(const int* __restrict__ cols, const float* __restrict__ vals,
                               const int* __restrict__ cnt, int CAP,
                               const int* __restrict__ selpos, float* __restrict__ Bcol, int ldb) {
    int row = blockIdx.x;
    float4* rowp = (float4*)(Bcol + (size_t)row * ldb);
    float4 z = {0.f, 0.f, 0.f, 0.f};
    for (int q = threadIdx.x; q < (ldb >> 2); q += blockDim.x) rowp[q] = z;
    __syncthreads();
    int nz = cnt[row];
    for (int e = threadIdx.x; e < nz; e += blockDim.x) {
        int c = cols[(size_t)row * CAP + e];
        if (c == row) continue;
        int j = selpos[c];
        if (j >= 0) Bcol[(size_t)row * ldb + j] = vals[(size_t)row * CAP + e];
    }
    if (threadIdx.x == 0) {
        int j = selpos[row];
        if (j >= 0) Bcol[(size_t)row * ldb + j] = 1.0f;
    }
}

__global__ void k_aug_part(const int* __restrict__ perm,
                           const int* __restrict__ colsS, const float* __restrict__ valsS,
                           const int* __restrict__ cntS, int CAPS,
                           const float* __restrict__ Bcol, int ldb, int kk,
                           float* __restrict__ T2p) {
    __shared__ int   scol[CAPMAX];
    __shared__ float sval[CAPMAX];
    int i = blockIdx.x, sp = blockIdx.y;
    int pi = perm[i];
    int nz = cntS[pi];
    for (int e = threadIdx.x; e < nz; e += blockDim.x) {
        int c = colsS[(size_t)pi * CAPS + e];
        scol[e] = c;
        sval[e] = (c == pi) ? 0.0f : valsS[(size_t)pi * CAPS + e];
    }
    __syncthreads();
    int j0 = threadIdx.x * 4;
    if (j0 >= ldb) return;
    int j4 = j0 >> 2;
    float4 a = {0.f, 0.f, 0.f, 0.f};
    if (sp == 0) a = ((const float4*)(Bcol + (size_t)pi * ldb))[j4];
    float4 acc1 = {0.f, 0.f, 0.f, 0.f};
    int e  = (nz * sp) / ESPLIT;
    int e1 = (nz * (sp + 1)) / ESPLIT;
    for (; e + 8 <= e1; e += 8) {
        float v0 = sval[e],     v1 = sval[e + 1], v2 = sval[e + 2], v3 = sval[e + 3];
        float v4 = sval[e + 4], v5 = sval[e + 5], v6 = sval[e + 6], v7 = sval[e + 7];
        float4 b0 = ((const float4*)(Bcol + (size_t)scol[e]     * ldb))[j4];
        float4 b1 = ((const float4*)(Bcol + (size_t)scol[e + 1] * ldb))[j4];
        float4 b2 = ((const float4*)(Bcol + (size_t)scol[e + 2] * ldb))[j4];
        float4 b3 = ((const float4*)(Bcol + (size_t)scol[e + 3] * ldb))[j4];
        float4 b4 = ((const float4*)(Bcol + (size_t)scol[e + 4] * ldb))[j4];
        float4 b5 = ((const float4*)(Bcol + (size_t)scol[e + 5] * ldb))[j4];
        float4 b6 = ((const float4*)(Bcol + (size_t)scol[e + 6] * ldb))[j4];
        float4 b7 = ((const float4*)(Bcol + (size_t)scol[e + 7] * ldb))[j4];
        a.x += v0 * b0.x + v1 * b1.x + v2 * b2.x + v3 * b3.x;
        a.y += v0 * b0.y + v1 * b1.y + v2 * b2.y + v3 * b3.y;
        a.z += v0 * b0.z + v1 * b1.z + v2 * b2.z + v3 * b3.z;
        a.w += v0 * b0.w + v1 * b1.w + v2 * b2.w + v3 * b3.w;
        acc1.x += v4 * b4.x + v5 * b5.x + v6 * b6.x + v7 * b7.x;
        acc1.y += v4 * b4.y + v5 * b5.y + v6 * b6.y + v7 * b7.y;
        acc1.z += v4 * b4.z + v5 * b5.z + v6 * b6.z + v7 * b7.z;
        acc1.w += v4 * b4.w + v5 * b5.w + v6 * b6.w + v7 * b7.w;
    }
    for (; e < e1; ++e) {
        float v = sval[e];
        float4 b = ((const float4*)(Bcol + (size_t)scol[e] * ldb))[j4];
        a.x += v * b.x; a.y += v * b.y; a.z += v * b.z; a.w += v * b.w;
    }
    a.x += acc1.x; a.y += acc1.y; a.z += acc1.z; a.w += acc1.w;
    *(float4*)(T2p + ((size_t)sp * KK2 + i) * ldb + j0) = a;
}

__global__ void k_csr2_build(const float* __restrict__ T2p,
                             int* __restrict__ cols, float* __restrict__ vals,
                             int* __restrict__ cnt, float* __restrict__ dinv,
                             const float* __restrict__ hp2, const float* __restrict__ W2,
                             float* __restrict__ g) {
    int row = blockIdx.x * (blockDim.x >> 6) + (threadIdx.x >> 6);
    int lane = threadIdx.x & 63;
    if (row >= KK2) return;
    const float* r0 = T2p + ((size_t)0 * KK2 + row) * KK2P;
    const float* r1 = T2p + ((size_t)1 * KK2 + row) * KK2P;
    const float* r2 = T2p + ((size_t)2 * KK2 + row) * KK2P;
    const float* r3 = T2p + ((size_t)3 * KK2 + row) * KK2P;
    int base = 0;
    float s = 0.0f;
    for (int c0 = 0; c0 < KK2; c0 += 64) {
        int c = c0 + lane;
        float v = 0.0f;
        if (c < KK2 && c != row) v = (r0[c] + r1[c]) + (r2[c] + r3[c]);
        unsigned long long mb = __ballot(v != 0.0f);
        if (v != 0.0f) {
            int idx = base + __popcll(mb & ((1ull << lane) - 1ull));
            if (idx < CAP2) {
                cols[(size_t)row * CAP2 + idx] = c;
                vals[(size_t)row * CAP2 + idx] = v;
            }
            s += v;
        }
        base += __popcll(mb);
    }
    for (int off = 32; off; off >>= 1) s += __shfl_xor(s, off, 64);
    float dv = rsqrtf(s + 2.0f);
    if (lane == 0) {
        cnt[row] = base < CAP2 ? base : CAP2;
        dinv[row] = dv;
    }
    const float* hrow = hp2 + (size_t)row * 64;
    float acc = 0.0f;
    for (int k = 0; k < 64; ++k) acc += hrow[k] * W2[k * 64 + lane];
    g[(size_t)row * 64 + lane] = dv * acc;
}

// ---------------- launch ----------------

extern "C" void kernel_launch(void* const* d_in, const int* in_sizes, int n_in,
                              void* d_out, int out_size, void* d_ws, size_t ws_size,
                              hipStream_t stream) {
    const float* x   = (const float*)d_in[0];
    const int*   ei  = (const int*)d_in[1];
    const float* W0  = (const float*)d_in[2];
    const float* b0  = (const float*)d_in[3];
    const float* W1  = (const float*)d_in[4];
    const float* b1  = (const float*)d_in[5];
    const float* W2  = (const float*)d_in[6];
    const float* b2  = (const float*)d_in[7];
    const float* p1  = (const float*)d_in[8];
    const float* p2  = (const float*)d_in[9];
    const float* Wu0 = (const float*)d_in[10];
    const float* bu0 = (const float*)d_in[11];
    const float* Wu1 = (const float*)d_in[12];
    const float* bu1 = (const float*)d_in[13];
    float* out = (float*)d_out;

    // ---- workspace layout (float units) ----
    float* fw = (float*)d_ws;
    size_t off = 0;
    int*   slots  = (int*)(fw + off); off += (size_t)NN * SLOT;
    int*   cntraw = (int*)(fw + off); off += NN;
    int*   cols0  = (int*)(fw + off); off += (size_t)NN * CAP0;
    float* vals0  = fw + off;         off += (size_t)NN * CAP0;
    int*   cols1  = (int*)(fw + off); off += (size_t)KK1 * CAP1;
    float* vals1  = fw + off;         off += (size_t)KK1 * CAP1;
    int*   cols2  = (int*)(fw + off); off += (size_t)KK2 * CAP2;
    float* vals2  = fw + off;         off += (size_t)KK2 * CAP2;
    int*   bc0C   = (int*)(fw + off); off += (size_t)NN * CAPB0;
    float* bc0V   = fw + off;         off += (size_t)NN * CAPB0;
    int*   bc0N   = (int*)(fw + off); off += NN;
    float* Bcol2  = fw + off;         off += (size_t)KK1 * KK2P;
    float* T2p    = fw + off;         off += (size_t)ESPLIT * KK2 * KK2P;
    int*   cnt0   = (int*)(fw + off); off += NN;
    int*   cnt1   = (int*)(fw + off); off += KK1;
    int*   cnt2   = (int*)(fw + off); off += KK2 + 2;
    float* g      = fw + off; off += (size_t)NN * HIDC;
    float* res0   = fw + off; off += (size_t)NN * HIDC;
    float* res1   = fw + off; off += (size_t)KK1 * HIDC;
    float* hp     = fw + off; off += (size_t)KK1 * HIDC;
    float* hp2    = fw + off; off += (size_t)KK2 * HIDC;
    float* x2     = fw + off; off += (size_t)KK2 * HIDC;
    float* xu     = fw + off; off += (size_t)KK1 * HIDC;
    float* sc1    = fw + off; off += NN;
    float* sc2    = fw + off; off += KK1;
    float* dinv0  = fw + off; off += NN;
    float* dinv1  = fw + off; off += KK1;
    float* dinv2  = fw + off; off += KK2 + 2;
    int* perm1    = (int*)(fw + off); off += KK1;
    int* perm2    = (int*)(fw + off); off += KK2 + 2;
    int* selpos1  = (int*)(fw + off); off += NN;
    int* selpos2  = (int*)(fw + off); off += KK1;
    if (ws_size < off * sizeof(float)) return;

    // ---- preferred path: single cooperative mega-kernel ----
    MegaP P;
    P.x = x; P.ei = ei;
    P.W0 = W0; P.b0 = b0; P.W1 = W1; P.b1 = b1; P.W2 = W2; P.b2 = b2;
    P.p1 = p1; P.p2 = p2; P.Wu0 = Wu0; P.bu0 = bu0; P.Wu1 = Wu1; P.bu1 = bu1;
    P.out = out;
    P.slots = slots; P.cntraw = cntraw;
    P.cols0 = cols0; P.vals0 = vals0; P.cnt0 = cnt0;
    P.cols1 = cols1; P.vals1 = vals1; P.cnt1 = cnt1;
    P.cols2 = cols2; P.vals2 = vals2; P.cnt2 = cnt2;
    P.bc0C = bc0C; P.bc0V = bc0V; P.bc0N = bc0N;
    P.Bcol2 = Bcol2; P.T2p = T2p;
    P.g = g; P.res0 = res0; P.res1 = res1; P.hp = hp; P.hp2 = hp2; P.x2 = x2; P.xu = xu;
    P.sc1 = sc1; P.sc2 = sc2; P.dinv0 = dinv0; P.dinv1 = dinv1; P.dinv2 = dinv2;
    P.perm1 = perm1; P.perm2 = perm2; P.selpos1 = selpos1; P.selpos2 = selpos2;

    void* args[] = { &P };
    hipError_t err = hipLaunchCooperativeKernel((const void*)k_mega, dim3(512), dim3(256),
                                                args, 0, stream);
    if (err == hipSuccess) return;

    // ---- fallback: proven 17-kernel sequence (r15) ----
    dim3 b64(64), b192(192), b256(256);

    k_zero_i32<<<dim3((NN + 255) / 256), b256, 0, stream>>>(cntraw, NN);
    k_edge_slots<<<dim3((EE + 255) / 256), b256, 0, stream>>>(ei, cntraw, slots);
    k_csr0_sort<<<dim3(NN / 4), b256, 0, stream>>>(cntraw, slots, cols0, vals0, cnt0, dinv0,
                                                   x, W0, g);
    k_gcn_agg_csr<<<dim3(NN), b256, 0, stream>>>(cols0, vals0, cnt0, CAP0, g, dinv0, b0, res0, NN, 64, 1, p1, sc1);
    k_topk<<<dim3(NN), b256, 0, stream>>>(sc1, res0, NN, KK1, perm1, selpos1, hp);
    k_bcolcsr<<<dim3(NN / 4), b256, 0, stream>>>(cols0, vals0, cnt0, CAP0, selpos1, NN, bc0C, bc0V, bc0N, CAPB0);
    k_aug_sparse<<<dim3(KK1), b256, 0, stream>>>(perm1, cols0, vals0, cnt0, CAP0,
                                                 bc0C, bc0V, bc0N, CAPB0, KK1,
                                                 cols1, vals1, cnt1, dinv1, CAP1,
                                                 hp, W1, g);
    k_gcn_agg_csr<<<dim3(KK1), b256, 0, stream>>>(cols1, vals1, cnt1, CAP1, g, dinv1, b1, res1, KK1, 64, 1, p2, sc2);
    k_topk<<<dim3(KK1), b256, 0, stream>>>(sc2, res1, KK1, KK2, perm2, selpos2, hp2);
    k_bcol_scatter<<<dim3(KK1), b256, 0, stream>>>(cols1, vals1, cnt1, CAP1, selpos2, Bcol2, KK2P);
    k_aug_part<<<dim3(KK2, ESPLIT), b192, 0, stream>>>(perm2, cols1, vals1, cnt1, CAP1,
                                                       Bcol2, KK2P, KK2, T2p);
    k_csr2_build<<<dim3((KK2 + 3) / 4), b256, 0, stream>>>(T2p, cols2, vals2, cnt2, dinv2,
                                                           hp2, W2, g);
    k_gcn_agg_csr<<<dim3(KK2), b256, 0, stream>>>(cols2, vals2, cnt2, CAP2, g, dinv2, b2, x2, KK2, 64, 1, nullptr, nullptr);
    k_xw_scale<<<dim3(KK1), b64, 0, stream>>>(res1, x2, selpos2, Wu0, dinv1, g, KK1, 64, 64);
    k_gcn_agg_csr<<<dim3(KK1), b256, 0, stream>>>(cols1, vals1, cnt1, CAP1, g, dinv1, bu0, xu, KK1, 64, 1, nullptr, nullptr);
    k_xw_scale<<<dim3(NN), b64, 0, stream>>>(res0, xu, selpos1, Wu1, dinv0, g, NN, 64, 16);
    k_gcn_agg_csr<<<dim3(NN), b256, 0, stream>>>(cols0, vals0, cnt0, CAP0, g, dinv0, bu1, out, NN, 16, 0, nullptr, nullptr);
}

// Round 17
// 144.493 us; speedup vs baseline: 7.7436x; 7.7436x over previous
//
#include <hip/hip_runtime.h>

#define NN   3000
#define EE   48000
#define KK1  1500
#define KK2  750
#define KK2P 752      // padded row stride (float4 alignment)
#define HIDC 64
#define SLOT 64       // max raw in-degree slots (mean 16; Poisson tail safe)
#define ESPLIT 4      // e-split factor for level-2 augment

#define CAP0  64      // CSR0 row capacity
#define CAP1  768     // CSR1 row capacity
#define CAP2  768     // CSR2 row capacity (>=750: lossless)
#define CAPMAX 768

// ---------------- kernels ----------------

__global__ void k_zero_i32(int* __restrict__ p, int n) {
    int i = blockIdx.x * blockDim.x + threadIdx.x;
    if (i < n) p[i] = 0;
}

// per-edge slot scatter: slots[t][idx] = s, idx = atomic count
__global__ void k_edge_slots(const int* __restrict__ ei, int* __restrict__ cntraw,
                             int* __restrict__ slots) {
    int e = blockIdx.x * blockDim.x + threadIdx.x;
    if (e >= EE) return;
    int s = ei[e];        // source
    int t = ei[EE + e];   // target
    int idx = atomicAdd(&cntraw[t], 1);
    if (idx < SLOT) slots[t * SLOT + idx] = s;
}

// wave per row: sort+dedup slot entries -> CSR0 (col asc, multiplicity vals) + dinv0.
// FUSED epilogue: g[row,:] = dinv0[row] * (x[row,:16] @ W0)
__global__ void k_csr0_sort(const int* __restrict__ cntraw, const int* __restrict__ slots,
                            int* __restrict__ cols, float* __restrict__ vals,
                            int* __restrict__ cnt, float* __restrict__ dinv,
                            const float* __restrict__ x, const float* __restrict__ W0,
                            float* __restrict__ g) {
    int row = blockIdx.x * (blockDim.x >> 6) + (threadIdx.x >> 6);   // 4 rows/block
    int lane = threadIdx.x & 63;
    int raw = cntraw[row];
    int nz = raw < SLOT ? raw : SLOT;
    int my = (lane < nz) ? slots[row * SLOT + lane] : 0x7FFFFFFF;
    int dup_before = 0, equal_total = 0;
    for (int f = 0; f < 64; ++f) {
        int cf = __shfl(my, f, 64);
        if (cf == my) { equal_total++; if (f < lane) dup_before++; }
    }
    bool leader = (lane < nz) && (dup_before == 0);
    unsigned long long lm = __ballot(leader);
    int dl = 0;
    unsigned long long m = lm;
    while (m) {                      // iterate leader lanes (wave-uniform sequence)
        int f = __builtin_ctzll(m); m &= m - 1;
        int cf = __shfl(my, f, 64);
        dl += (cf < my);
    }
    if (leader) {
        cols[(size_t)row * CAP0 + dl] = my;
        vals[(size_t)row * CAP0 + dl] = (float)equal_total;   // duplicate edges sum
    }
    float dv = rsqrtf((float)raw + 2.0f);                     // in-degree + self-loop wt 2
    if (lane == 0) {
        cnt[row] = __popcll(lm);
        dinv[row] = dv;
    }
    // fused xw0 (IC=16, OC=64)
    float acc = 0.0f;
#pragma unroll
    for (int k = 0; k < 16; ++k) acc += x[(size_t)row * 16 + k] * W0[k * 64 + lane];
    g[(size_t)row * 64 + lane] = dv * acc;
}

// g[i,:] = dinv[i] * ((h[i,:] + up[selpos[i],:]) @ W); block=64, grid=n
__global__ void k_xw_scale(const float* __restrict__ h, const float* __restrict__ up,
                           const int* __restrict__ selpos,
                           const float* __restrict__ W, const float* __restrict__ dinv,
                           float* __restrict__ g, int n, int IC, int OC) {
    int row = blockIdx.x;
    int c = threadIdx.x;
    __shared__ float hr[64];
    if (c < IC) {
        float v = h[(size_t)row * IC + c];
        if (selpos) {
            int sp = selpos[row];
            if (sp >= 0) v += up[(size_t)sp * IC + c];
        }
        hr[c] = v;
    }
    __syncthreads();
    if (c >= OC) return;
    float acc = 0.0f;
    for (int k = 0; k < IC; ++k) acc += hr[k] * W[k * OC + c];
    g[(size_t)row * OC + c] = dinv[row] * acc;
}

// out[t,:] = act( dinv[t] * ( sum_e val_e * g[col_e,:] + 2*g[t,:] ) + b )
// Block per row, 4 waves split nonzeros (32-entry rounds, 8-ILP), LDS reduce;
// wave 0 finishes + optional fused TopK score (C==64).
__global__ void k_gcn_agg_csr(const int* __restrict__ cols, const float* __restrict__ vals,
                              const int* __restrict__ cnt, int CAP,
                              const float* __restrict__ g, const float* __restrict__ dinv,
                              const float* __restrict__ bias, float* __restrict__ out,
                              int n, int C, int do_tanh,
                              const float* __restrict__ p, float* __restrict__ score) {
    int row = blockIdx.x;
    int w = threadIdx.x >> 6;
    int lane = threadIdx.x & 63;
    int nz = cnt[row];
    const int*   rc = cols + (size_t)row * CAP;
    const float* rv = vals + (size_t)row * CAP;
    bool act = lane < C;
    float a0 = 0.f, a1 = 0.f, a2 = 0.f, a3 = 0.f;
    float a4 = 0.f, a5 = 0.f, a6 = 0.f, a7 = 0.f;
    for (int e = 8 * w; e + 8 <= nz; e += 32) {
        int   c0 = rc[e],     c1 = rc[e + 1], c2 = rc[e + 2], c3 = rc[e + 3];
        int   c4 = rc[e + 4], c5 = rc[e + 5], c6 = rc[e + 6], c7 = rc[e + 7];
        float v0 = rv[e],     v1 = rv[e + 1], v2 = rv[e + 2], v3 = rv[e + 3];
        float v4 = rv[e + 4], v5 = rv[e + 5], v6 = rv[e + 6], v7 = rv[e + 7];
        if (act) {
            a0 += v0 * g[(size_t)c0 * C + lane];
            a1 += v1 * g[(size_t)c1 * C + lane];
            a2 += v2 * g[(size_t)c2 * C + lane];
            a3 += v3 * g[(size_t)c3 * C + lane];
            a4 += v4 * g[(size_t)c4 * C + lane];
            a5 += v5 * g[(size_t)c5 * C + lane];
            a6 += v6 * g[(size_t)c6 * C + lane];
            a7 += v7 * g[(size_t)c7 * C + lane];
        }
    }
    if (w == 0) {  // tail (< 8 entries)
        for (int e = nz & ~7; e < nz; ++e)
            if (act) a0 += rv[e] * g[(size_t)rc[e] * C + lane];
    }
    __shared__ float red[4][64];
    red[w][lane] = ((a0 + a1) + (a2 + a3)) + ((a4 + a5) + (a6 + a7));
    __syncthreads();
    if (w == 0) {
        float o = 0.f;
        if (act) {
            float a = (red[0][lane] + red[1][lane]) + (red[2][lane] + red[3][lane])
                    + 2.0f * g[(size_t)row * C + lane];
            o = dinv[row] * a + bias[lane];
            if (do_tanh) o = tanhf(o);
            out[(size_t)row * C + lane] = o;
        }
        if (p) {  // fused score = tanh((row . p) * rsqrt(p.p)); C==64 here
            float pv = p[lane];
            float d = o * pv, pp = pv * pv;
            for (int off = 32; off; off >>= 1) {
                d  += __shfl_down(d, off, 64);
                pp += __shfl_down(pp, off, 64);
            }
            if (lane == 0) score[row] = tanhf(d * rsqrtf(pp));
        }
    }
}

// exact jax.lax.top_k order (value desc, index asc), rank-count; fused pool:
// block per candidate i; selpos[i] = rank (or -1); if selected, writes
// hp[rank,:] = h[i,:] * score[i].
__global__ void k_topk(const float* __restrict__ score, const float* __restrict__ h,
                       int n, int k, int* __restrict__ perm, int* __restrict__ selpos,
                       float* __restrict__ hp) {
    int i = blockIdx.x;
    float si = score[i];
    int r = 0;
    for (int j = threadIdx.x; j < n; j += blockDim.x) {
        float sj = score[j];
        r += (sj > si) || (sj == si && j < i);
    }
    int lane = threadIdx.x & 63, wid = threadIdx.x >> 6;
    for (int off = 32; off; off >>= 1) r += __shfl_down(r, off, 64);
    __shared__ int red[4];
    __shared__ int srank;
    if (lane == 0) red[wid] = r;
    __syncthreads();
    if (threadIdx.x == 0) {
        int rank = red[0] + red[1] + red[2] + red[3];
        srank = rank;
        selpos[i] = (rank < k) ? rank : -1;
        if (rank < k) perm[rank] = i;
    }
    __syncthreads();
    int rank = srank;
    if (rank < k && threadIdx.x < HIDC)
        hp[(size_t)rank * HIDC + threadIdx.x] = h[(size_t)i * HIDC + threadIdx.x] * si;
}

// Sparse x sparse augment (level 0->1, nz ~16) with INLINE column filtering:
// for each neighbor k of pi (plus implicit diag k=pi, kv=1), scatter
// kv * B[k, selected] into dense LDS row, where B[k,:] = T0[k,:] offdiag + I.
// Filtering = selpos lookup per entry (no prebuilt filtered CSR).
// Exact-integer atomics -> order-independent, deterministic.
// FUSED: wave 1 computes g[i,:] = dinv1[i] * (hp[i,:] @ W1) during compaction.
__global__ void k_aug_sparse(const int* __restrict__ perm,
                             const int* __restrict__ colsS, const float* __restrict__ valsS,
                             const int* __restrict__ cntS, int CAPS,
                             const int* __restrict__ selpos, int kk,
                             int* __restrict__ colsD, float* __restrict__ valsD,
                             int* __restrict__ cntD, float* __restrict__ dinvD, int CAPD,
                             const float* __restrict__ hp, const float* __restrict__ W,
                             float* __restrict__ gOut) {
    __shared__ float srow[1504];
    __shared__ float ssum[4];
    int i = blockIdx.x;
    int pi = perm[i];
    int nzS = cntS[pi];
    for (int t = threadIdx.x; t < 1504; t += blockDim.x) srow[t] = 0.0f;
    __syncthreads();
    int w = threadIdx.x >> 6, lane = threadIdx.x & 63;
    // ee in [0, nzS]; ee == nzS is the implicit diag entry (k=pi, kv=1)
    for (int ee = w; ee <= nzS; ee += 4) {
        int k; float kv;
        if (ee == nzS) { k = pi; kv = 1.0f; }
        else {
            k = colsS[(size_t)pi * CAPS + ee];
            if (k == pi) continue;               // original diag replaced by implicit 1
            kv = valsS[(size_t)pi * CAPS + ee];
        }
        // inline filtered row of B[k,:]: offdiag entries of T0[k,:] + diag 1
        int nzk = cntS[k];
        for (int t = lane; t < nzk; t += 64) {
            int c = colsS[(size_t)k * CAPS + t];
            if (c == k) continue;
            int j = selpos[c];
            if (j >= 0) atomicAdd(&srow[j], kv * valsS[(size_t)k * CAPS + t]);
        }
        if (lane == 0) {
            int jd = selpos[k];
            if (jd >= 0) atomicAdd(&srow[jd], kv);   // B diag = 1
        }
    }
    __syncthreads();
    if (threadIdx.x == 0) srow[i] = 0.0f;        // zero output diag
    __syncthreads();
    float psum = 0.0f;
    for (int t = threadIdx.x; t < kk; t += blockDim.x) psum += srow[t];
    for (int off = 32; off; off >>= 1) psum += __shfl_down(psum, off, 64);
    if (lane == 0) ssum[w] = psum;
    __syncthreads();
    if (w == 0) {
        if (lane == 0)
            dinvD[i] = rsqrtf((ssum[0] + ssum[1]) + (ssum[2] + ssum[3]) + 2.0f);
        int base = 0;
        for (int c0 = 0; c0 < kk; c0 += 64) {
            int c = c0 + lane;
            float v = (c < kk) ? srow[c] : 0.0f;
            unsigned long long mb = __ballot(v != 0.0f);
            if (v != 0.0f) {
                int idx = base + __popcll(mb & ((1ull << lane) - 1ull));
                if (idx < CAPD) {
                    colsD[(size_t)i * CAPD + idx] = c;
                    valsD[(size_t)i * CAPD + idx] = v;
                }
            }
            base += __popcll(mb);
        }
        if (lane == 0) cntD[i] = base < CAPD ? base : CAPD;
    } else if (w == 1) {
        // fused xw1: g[i,:] = dinv1[i] * (hp[i,:] @ W)  (IC=OC=64)
        float dv = rsqrtf((ssum[0] + ssum[1]) + (ssum[2] + ssum[3]) + 2.0f);
        const float* hrow = hp + (size_t)i * 64;
        float acc = 0.0f;
        for (int k = 0; k < 64; ++k) acc += hrow[k] * W[k * 64 + lane];
        gOut[(size_t)i * 64 + lane] = dv * acc;
    }
}

// Dense Bcol panel with FUSED zero-fill: block per row, zero the row at full BW,
// sync, then scatter CSR nonzeros (diag forced 1).
__global__ void k_bcol_scatter(const int* __restrict__ cols, const float* __restrict__ vals,
                               const int* __restrict__ cnt, int CAP,
                               const int* __restrict__ selpos, float* __restrict__ Bcol, int ldb) {
    int row = blockIdx.x;
    float4* rowp = (float4*)(Bcol + (size_t)row * ldb);
    float4 z = {0.f, 0.f, 0.f, 0.f};
    for (int q = threadIdx.x; q < (ldb >> 2); q += blockDim.x) rowp[q] = z;
    __syncthreads();
    int nz = cnt[row];
    for (int e = threadIdx.x; e < nz; e += blockDim.x) {
        int c = cols[(size_t)row * CAP + e];
        if (c == row) continue;                 // diag handled below
        int j = selpos[c];
        if (j >= 0) Bcol[(size_t)row * ldb + j] = vals[(size_t)row * CAP + e];
    }
    if (threadIdx.x == 0) {
        int j = selpos[row];
        if (j >= 0) Bcol[(size_t)row * ldb + j] = 1.0f;  // B diag = 1
    }
}

// Level-2 augment, e-split partials: grid (KK2, ESPLIT). Block (192) computes a
// PARTIAL dense row over its nonzero sub-range (8-ILP float4 gather) and stores
// it to T2p[split][i][:] with plain stores (no atomics; deterministic).
// Split 0 carries the implicit-diag term (1 * Bcol[pi][:]).
__global__ void k_aug_part(const int* __restrict__ perm,
                           const int* __restrict__ colsS, const float* __restrict__ valsS,
                           const int* __restrict__ cntS, int CAPS,
                           const float* __restrict__ Bcol, int ldb, int kk,
                           float* __restrict__ T2p) {
    __shared__ int   scol[CAPMAX];
    __shared__ float sval[CAPMAX];
    int i = blockIdx.x, sp = blockIdx.y;
    int pi = perm[i];
    int nz = cntS[pi];
    for (int e = threadIdx.x; e < nz; e += blockDim.x) {
        int c = colsS[(size_t)pi * CAPS + e];
        scol[e] = c;
        sval[e] = (c == pi) ? 0.0f : valsS[(size_t)pi * CAPS + e];  // diag via Bcol[pi] term
    }
    __syncthreads();
    int j0 = threadIdx.x * 4;
    if (j0 >= ldb) return;
    int j4 = j0 >> 2;
    float4 a = {0.f, 0.f, 0.f, 0.f};
    if (sp == 0) a = ((const float4*)(Bcol + (size_t)pi * ldb))[j4];  // 1 * B[pi, perm[j..j+3]]
    float4 acc1 = {0.f, 0.f, 0.f, 0.f};
    int e  = (nz * sp) / ESPLIT;
    int e1 = (nz * (sp + 1)) / ESPLIT;
    for (; e + 8 <= e1; e += 8) {
        float v0 = sval[e],     v1 = sval[e + 1], v2 = sval[e + 2], v3 = sval[e + 3];
        float v4 = sval[e + 4], v5 = sval[e + 5], v6 = sval[e + 6], v7 = sval[e + 7];
        float4 b0 = ((const float4*)(Bcol + (size_t)scol[e]     * ldb))[j4];
        float4 b1 = ((const float4*)(Bcol + (size_t)scol[e + 1] * ldb))[j4];
        float4 b2 = ((const float4*)(Bcol + (size_t)scol[e + 2] * ldb))[j4];
        float4 b3 = ((const float4*)(Bcol + (size_t)scol[e + 3] * ldb))[j4];
        float4 b4 = ((const float4*)(Bcol + (size_t)scol[e + 4] * ldb))[j4];
        float4 b5 = ((const float4*)(Bcol + (size_t)scol[e + 5] * ldb))[j4];
        float4 b6 = ((const float4*)(Bcol + (size_t)scol[e + 6] * ldb))[j4];
        float4 b7 = ((const float4*)(Bcol + (size_t)scol[e + 7] * ldb))[j4];
        a.x += v0 * b0.x + v1 * b1.x + v2 * b2.x + v3 * b3.x;
        a.y += v0 * b0.y + v1 * b1.y + v2 * b2.y + v3 * b3.y;
        a.z += v0 * b0.z + v1 * b1.z + v2 * b2.z + v3 * b3.z;
        a.w += v0 * b0.w + v1 * b1.w + v2 * b2.w + v3 * b3.w;
        acc1.x += v4 * b4.x + v5 * b5.x + v6 * b6.x + v7 * b7.x;
        acc1.y += v4 * b4.y + v5 * b5.y + v6 * b6.y + v7 * b7.y;
        acc1.z += v4 * b4.z + v5 * b5.z + v6 * b6.z + v7 * b7.z;
        acc1.w += v4 * b4.w + v5 * b5.w + v6 * b6.w + v7 * b7.w;
    }
    for (; e < e1; ++e) {
        float v = sval[e];
        float4 b = ((const float4*)(Bcol + (size_t)scol[e] * ldb))[j4];
        a.x += v * b.x; a.y += v * b.y; a.z += v * b.z; a.w += v * b.w;
    }
    a.x += acc1.x; a.y += acc1.y; a.z += acc1.z; a.w += acc1.w;
    *(float4*)(T2p + ((size_t)sp * KK2 + i) * ldb + j0) = a;
}

// Sum ESPLIT partial slices, zero diag, compact to CSR2, rowsum -> dinv2.
// Wave per row (4 rows/block). FUSED: g[row,:] = dinv2[row] * (hp2[row,:] @ W2).
__global__ void k_csr2_build(const float* __restrict__ T2p,
                             int* __restrict__ cols, float* __restrict__ vals,
                             int* __restrict__ cnt, float* __restrict__ dinv,
                             const float* __restrict__ hp2, const float* __restrict__ W2,
                             float* __restrict__ g) {
    int row = blockIdx.x * (blockDim.x >> 6) + (threadIdx.x >> 6);
    int lane = threadIdx.x & 63;
    if (row >= KK2) return;
    const float* r0 = T2p + ((size_t)0 * KK2 + row) * KK2P;
    const float* r1 = T2p + ((size_t)1 * KK2 + row) * KK2P;
    const float* r2 = T2p + ((size_t)2 * KK2 + row) * KK2P;
    const float* r3 = T2p + ((size_t)3 * KK2 + row) * KK2P;
    int base = 0;
    float s = 0.0f;
    for (int c0 = 0; c0 < KK2; c0 += 64) {
        int c = c0 + lane;
        float v = 0.0f;
        if (c < KK2 && c != row) v = (r0[c] + r1[c]) + (r2[c] + r3[c]);
        unsigned long long mb = __ballot(v != 0.0f);
        if (v != 0.0f) {
            int idx = base + __popcll(mb & ((1ull << lane) - 1ull));
            if (idx < CAP2) {
                cols[(size_t)row * CAP2 + idx] = c;
                vals[(size_t)row * CAP2 + idx] = v;
            }
            s += v;
        }
        base += __popcll(mb);
    }
    for (int off = 32; off; off >>= 1) s += __shfl_xor(s, off, 64);  // all-lanes total
    float dv = rsqrtf(s + 2.0f);
    if (lane == 0) {
        cnt[row] = base < CAP2 ? base : CAP2;
        dinv[row] = dv;
    }
    // fused xw2 (IC=OC=64)
    const float* hrow = hp2 + (size_t)row * 64;
    float acc = 0.0f;
    for (int k = 0; k < 64; ++k) acc += hrow[k] * W2[k * 64 + lane];
    g[(size_t)row * 64 + lane] = dv * acc;
}

// ---------------- launch ----------------

extern "C" void kernel_launch(void* const* d_in, const int* in_sizes, int n_in,
                              void* d_out, int out_size, void* d_ws, size_t ws_size,
                              hipStream_t stream) {
    const float* x   = (const float*)d_in[0];
    const int*   ei  = (const int*)d_in[1];
    const float* W0  = (const float*)d_in[2];
    const float* b0  = (const float*)d_in[3];
    const float* W1  = (const float*)d_in[4];
    const float* b1  = (const float*)d_in[5];
    const float* W2  = (const float*)d_in[6];
    const float* b2  = (const float*)d_in[7];
    const float* p1  = (const float*)d_in[8];
    const float* p2  = (const float*)d_in[9];
    const float* Wu0 = (const float*)d_in[10];
    const float* bu0 = (const float*)d_in[11];
    const float* Wu1 = (const float*)d_in[12];
    const float* bu1 = (const float*)d_in[13];
    float* out = (float*)d_out;

    // ---- workspace layout (float units) ----
    float* fw = (float*)d_ws;
    size_t off = 0;
    int*   slots  = (int*)(fw + off); off += (size_t)NN * SLOT;
    int*   cntraw = (int*)(fw + off); off += NN;
    int*   cols0  = (int*)(fw + off); off += (size_t)NN * CAP0;
    float* vals0  = fw + off;         off += (size_t)NN * CAP0;
    int*   cols1  = (int*)(fw + off); off += (size_t)KK1 * CAP1;
    float* vals1  = fw + off;         off += (size_t)KK1 * CAP1;
    int*   cols2  = (int*)(fw + off); off += (size_t)KK2 * CAP2;
    float* vals2  = fw + off;         off += (size_t)KK2 * CAP2;
    float* Bcol2  = fw + off;         off += (size_t)KK1 * KK2P;
    float* T2p    = fw + off;         off += (size_t)ESPLIT * KK2 * KK2P;
    int*   cnt0   = (int*)(fw + off); off += NN;
    int*   cnt1   = (int*)(fw + off); off += KK1;
    int*   cnt2   = (int*)(fw + off); off += KK2 + 2;
    float* g      = fw + off; off += (size_t)NN * HIDC;
    float* res0   = fw + off; off += (size_t)NN * HIDC;
    float* res1   = fw + off; off += (size_t)KK1 * HIDC;
    float* hp     = fw + off; off += (size_t)KK1 * HIDC;
    float* hp2    = fw + off; off += (size_t)KK2 * HIDC;
    float* x2     = fw + off; off += (size_t)KK2 * HIDC;
    float* xu     = fw + off; off += (size_t)KK1 * HIDC;
    float* sc1    = fw + off; off += NN;
    float* sc2    = fw + off; off += KK1;
    float* dinv0  = fw + off; off += NN;
    float* dinv1  = fw + off; off += KK1;
    float* dinv2  = fw + off; off += KK2 + 2;
    int* perm1    = (int*)(fw + off); off += KK1;
    int* perm2    = (int*)(fw + off); off += KK2 + 2;
    int* selpos1  = (int*)(fw + off); off += NN;
    int* selpos2  = (int*)(fw + off); off += KK1;
    if (ws_size < off * sizeof(float)) return;

    dim3 b64(64), b192(192), b256(256);

    // ---- CSR0 + dinv0 + g0 directly from edge list
    k_zero_i32<<<dim3((NN + 255) / 256), b256, 0, stream>>>(cntraw, NN);
    k_edge_slots<<<dim3((EE + 255) / 256), b256, 0, stream>>>(ei, cntraw, slots);
    k_csr0_sort<<<dim3(NN / 4), b256, 0, stream>>>(cntraw, slots, cols0, vals0, cnt0, dinv0,
                                                   x, W0, g);

    // ---- GCN0 -> res0 (+score sc1)
    k_gcn_agg_csr<<<dim3(NN), b256, 0, stream>>>(cols0, vals0, cnt0, CAP0, g, dinv0, b0, res0, NN, 64, 1, p1, sc1);

    // ---- pool 1 (topk + pool fused), sparse augment w/ inline filter (+fused xw1)
    k_topk<<<dim3(NN), b256, 0, stream>>>(sc1, res0, NN, KK1, perm1, selpos1, hp);
    k_aug_sparse<<<dim3(KK1), b256, 0, stream>>>(perm1, cols0, vals0, cnt0, CAP0,
                                                 selpos1, KK1,
                                                 cols1, vals1, cnt1, dinv1, CAP1,
                                                 hp, W1, g);

    // ---- GCN1 -> res1 (+score sc2)
    k_gcn_agg_csr<<<dim3(KK1), b256, 0, stream>>>(cols1, vals1, cnt1, CAP1, g, dinv1, b1, res1, KK1, 64, 1, p2, sc2);

    // ---- pool 2, e-split dense-gather augment -> CSR2, dinv2, g2 (fused xw2)
    k_topk<<<dim3(KK1), b256, 0, stream>>>(sc2, res1, KK1, KK2, perm2, selpos2, hp2);
    k_bcol_scatter<<<dim3(KK1), b256, 0, stream>>>(cols1, vals1, cnt1, CAP1, selpos2, Bcol2, KK2P);
    k_aug_part<<<dim3(KK2, ESPLIT), b192, 0, stream>>>(perm2, cols1, vals1, cnt1, CAP1,
                                                       Bcol2, KK2P, KK2, T2p);
    k_csr2_build<<<dim3((KK2 + 3) / 4), b256, 0, stream>>>(T2p, cols2, vals2, cnt2, dinv2,
                                                           hp2, W2, g);

    // ---- GCN2 -> x2
    k_gcn_agg_csr<<<dim3(KK2), b256, 0, stream>>>(cols2, vals2, cnt2, CAP2, g, dinv2, b2, x2, KK2, 64, 1, nullptr, nullptr);

    // ---- up to level 1: h = res1 + up(x2 via selpos2); GCN(Wu0) -> xu
    k_xw_scale<<<dim3(KK1), b64, 0, stream>>>(res1, x2, selpos2, Wu0, dinv1, g, KK1, 64, 64);
    k_gcn_agg_csr<<<dim3(KK1), b256, 0, stream>>>(cols1, vals1, cnt1, CAP1, g, dinv1, bu0, xu, KK1, 64, 1, nullptr, nullptr);

    // ---- up to level 0: h = res0 + up(xu via selpos1); GCN(Wu1) -> out (no tanh)
    k_xw_scale<<<dim3(NN), b64, 0, stream>>>(res0, xu, selpos1, Wu1, dinv0, g, NN, 64, 16);
    k_gcn_agg_csr<<<dim3(NN), b256, 0, stream>>>(cols0, vals0, cnt0, CAP0, g, dinv0, bu1, out, NN, 16, 0, nullptr, nullptr);
}

// Round 18
// 142.349 us; speedup vs baseline: 7.8602x; 1.0151x over previous
//
#include <hip/hip_runtime.h>

#define NN   3000
#define EE   48000
#define KK1  1500
#define KK2  750
#define KK2P 752      // padded row stride (float4 alignment)
#define HIDC 64
#define SLOT 64       // max raw in-degree slots (mean 16; Poisson tail safe)
#define ESPLIT 4      // e-split factor for level-2 augment

#define CAP0  64      // CSR0 row capacity
#define CAP1  768     // CSR1 row capacity
#define CAP2  768     // CSR2 row capacity (>=750: lossless)
#define CAPB0 64      // filtered-CSR capacity, level 0 -> 1
#define CAPMAX 768

// ---------------- kernels ----------------

__global__ void k_zero_i32(int* __restrict__ p, int n) {
    int i = blockIdx.x * blockDim.x + threadIdx.x;
    if (i < n) p[i] = 0;
}

// per-edge slot scatter: slots[t][idx] = s, idx = atomic count
__global__ void k_edge_slots(const int* __restrict__ ei, int* __restrict__ cntraw,
                             int* __restrict__ slots) {
    int e = blockIdx.x * blockDim.x + threadIdx.x;
    if (e >= EE) return;
    int s = ei[e];        // source
    int t = ei[EE + e];   // target
    int idx = atomicAdd(&cntraw[t], 1);
    if (idx < SLOT) slots[t * SLOT + idx] = s;
}

// wave per row: sort+dedup slot entries -> CSR0 (col asc, multiplicity vals) + dinv0.
// FUSED epilogue: g[row,:] = dinv0[row] * (x[row,:16] @ W0)  (xw_scale level 0)
__global__ void k_csr0_sort(const int* __restrict__ cntraw, const int* __restrict__ slots,
                            int* __restrict__ cols, float* __restrict__ vals,
                            int* __restrict__ cnt, float* __restrict__ dinv,
                            const float* __restrict__ x, const float* __restrict__ W0,
                            float* __restrict__ g) {
    int row = blockIdx.x * (blockDim.x >> 6) + (threadIdx.x >> 6);   // 4 rows/block
    int lane = threadIdx.x & 63;
    int raw = cntraw[row];
    int nz = raw < SLOT ? raw : SLOT;
    int my = (lane < nz) ? slots[row * SLOT + lane] : 0x7FFFFFFF;
    int dup_before = 0, equal_total = 0;
    for (int f = 0; f < 64; ++f) {
        int cf = __shfl(my, f, 64);
        if (cf == my) { equal_total++; if (f < lane) dup_before++; }
    }
    bool leader = (lane < nz) && (dup_before == 0);
    unsigned long long lm = __ballot(leader);
    int dl = 0;
    unsigned long long m = lm;
    while (m) {                      // iterate leader lanes (wave-uniform sequence)
        int f = __builtin_ctzll(m); m &= m - 1;
        int cf = __shfl(my, f, 64);
        dl += (cf < my);
    }
    if (leader) {
        cols[(size_t)row * CAP0 + dl] = my;
        vals[(size_t)row * CAP0 + dl] = (float)equal_total;   // duplicate edges sum
    }
    float dv = rsqrtf((float)raw + 2.0f);                     // in-degree + self-loop wt 2
    if (lane == 0) {
        cnt[row] = __popcll(lm);
        dinv[row] = dv;
    }
    // fused xw0 (IC=16, OC=64)
    float acc = 0.0f;
#pragma unroll
    for (int k = 0; k < 16; ++k) acc += x[(size_t)row * 16 + k] * W0[k * 64 + lane];
    g[(size_t)row * 64 + lane] = dv * acc;
}

// g[i,:] = dinv[i] * ((h[i,:] + up[selpos[i],:]) @ W); block=64, grid=n
__global__ void k_xw_scale(const float* __restrict__ h, const float* __restrict__ up,
                           const int* __restrict__ selpos,
                           const float* __restrict__ W, const float* __restrict__ dinv,
                           float* __restrict__ g, int n, int IC, int OC) {
    int row = blockIdx.x;
    int c = threadIdx.x;
    __shared__ float hr[64];
    if (c < IC) {
        float v = h[(size_t)row * IC + c];
        if (selpos) {
            int sp = selpos[row];
            if (sp >= 0) v += up[(size_t)sp * IC + c];
        }
        hr[c] = v;
    }
    __syncthreads();
    if (c >= OC) return;
    float acc = 0.0f;
    for (int k = 0; k < IC; ++k) acc += hr[k] * W[k * OC + c];
    g[(size_t)row * OC + c] = dinv[row] * acc;
}

// out[t,:] = act( dinv[t] * ( sum_e val_e * g[col_e,:] + 2*g[t,:] ) + b )
// Block per row, 4 waves split nonzeros (32-entry rounds, 8-ILP), LDS reduce;
// wave 0 finishes + optional fused TopK score (C==64).
__global__ void k_gcn_agg_csr(const int* __restrict__ cols, const float* __restrict__ vals,
                              const int* __restrict__ cnt, int CAP,
                              const float* __restrict__ g, const float* __restrict__ dinv,
                              const float* __restrict__ bias, float* __restrict__ out,
                              int n, int C, int do_tanh,
                              const float* __restrict__ p, float* __restrict__ score) {
    int row = blockIdx.x;
    int w = threadIdx.x >> 6;
    int lane = threadIdx.x & 63;
    int nz = cnt[row];
    const int*   rc = cols + (size_t)row * CAP;
    const float* rv = vals + (size_t)row * CAP;
    bool act = lane < C;
    float a0 = 0.f, a1 = 0.f, a2 = 0.f, a3 = 0.f;
    float a4 = 0.f, a5 = 0.f, a6 = 0.f, a7 = 0.f;
    for (int e = 8 * w; e + 8 <= nz; e += 32) {
        int   c0 = rc[e],     c1 = rc[e + 1], c2 = rc[e + 2], c3 = rc[e + 3];
        int   c4 = rc[e + 4], c5 = rc[e + 5], c6 = rc[e + 6], c7 = rc[e + 7];
        float v0 = rv[e],     v1 = rv[e + 1], v2 = rv[e + 2], v3 = rv[e + 3];
        float v4 = rv[e + 4], v5 = rv[e + 5], v6 = rv[e + 6], v7 = rv[e + 7];
        if (act) {
            a0 += v0 * g[(size_t)c0 * C + lane];
            a1 += v1 * g[(size_t)c1 * C + lane];
            a2 += v2 * g[(size_t)c2 * C + lane];
            a3 += v3 * g[(size_t)c3 * C + lane];
            a4 += v4 * g[(size_t)c4 * C + lane];
            a5 += v5 * g[(size_t)c5 * C + lane];
            a6 += v6 * g[(size_t)c6 * C + lane];
            a7 += v7 * g[(size_t)c7 * C + lane];
        }
    }
    if (w == 0) {  // tail (< 8 entries)
        for (int e = nz & ~7; e < nz; ++e)
            if (act) a0 += rv[e] * g[(size_t)rc[e] * C + lane];
    }
    __shared__ float red[4][64];
    red[w][lane] = ((a0 + a1) + (a2 + a3)) + ((a4 + a5) + (a6 + a7));
    __syncthreads();
    if (w == 0) {
        float o = 0.f;
        if (act) {
            float a = (red[0][lane] + red[1][lane]) + (red[2][lane] + red[3][lane])
                    + 2.0f * g[(size_t)row * C + lane];
            o = dinv[row] * a + bias[lane];
            if (do_tanh) o = tanhf(o);
            out[(size_t)row * C + lane] = o;
        }
        if (p) {  // fused score = tanh((row . p) * rsqrt(p.p)); C==64 here
            float pv = p[lane];
            float d = o * pv, pp = pv * pv;
            for (int off = 32; off; off >>= 1) {
                d  += __shfl_down(d, off, 64);
                pp += __shfl_down(pp, off, 64);
            }
            if (lane == 0) score[row] = tanhf(d * rsqrtf(pp));
        }
    }
}

// exact jax.lax.top_k order (value desc, index asc), rank-count; fused pool:
// block per candidate i; selpos[i] = rank (or -1); if selected, writes
// hp[rank,:] = h[i,:] * score[i].
__global__ void k_topk(const float* __restrict__ score, const float* __restrict__ h,
                       int n, int k, int* __restrict__ perm, int* __restrict__ selpos,
                       float* __restrict__ hp) {
    int i = blockIdx.x;
    float si = score[i];
    int r = 0;
    for (int j = threadIdx.x; j < n; j += blockDim.x) {
        float sj = score[j];
        r += (sj > si) || (sj == si && j < i);
    }
    int lane = threadIdx.x & 63, wid = threadIdx.x >> 6;
    for (int off = 32; off; off >>= 1) r += __shfl_down(r, off, 64);
    __shared__ int red[4];
    __shared__ int srank;
    if (lane == 0) red[wid] = r;
    __syncthreads();
    if (threadIdx.x == 0) {
        int rank = red[0] + red[1] + red[2] + red[3];
        srank = rank;
        selpos[i] = (rank < k) ? rank : -1;
        if (rank < k) perm[rank] = i;
    }
    __syncthreads();
    int rank = srank;
    if (rank < k && threadIdx.x < HIDC)
        hp[(size_t)rank * HIDC + threadIdx.x] = h[(size_t)i * HIDC + threadIdx.x] * si;
}

// Filtered CSR of B (= T offdiag + I) restricted to selected columns, remapped
// to compact j indices. Wave per row (4/block). Col-ascending, deterministic.
__global__ void k_bcolcsr(const int* __restrict__ cols, const float* __restrict__ vals,
                          const int* __restrict__ cnt, int CAPS,
                          const int* __restrict__ selpos, int n,
                          int* __restrict__ bcC, float* __restrict__ bcV,
                          int* __restrict__ bcN, int CAPB) {
    int row = blockIdx.x * (blockDim.x >> 6) + (threadIdx.x >> 6);
    int lane = threadIdx.x & 63;
    if (row >= n) return;
    int nz = cnt[row];
    int base = 0;
    for (int e0 = 0; e0 < nz; e0 += 64) {
        int e = e0 + lane;
        int j = -1; float v = 0.0f;
        if (e < nz) {
            int c = cols[(size_t)row * CAPS + e];
            if (c != row) { j = selpos[c]; v = vals[(size_t)row * CAPS + e]; }
        }
        unsigned long long mb = __ballot(j >= 0);
        if (j >= 0) {
            int idx = base + __popcll(mb & ((1ull << lane) - 1ull));
            if (idx < CAPB) { bcC[(size_t)row * CAPB + idx] = j; bcV[(size_t)row * CAPB + idx] = v; }
        }
        base += __popcll(mb);
    }
    if (lane == 0) {
        int jd = selpos[row];
        if (jd >= 0 && base < CAPB) {
            bcC[(size_t)row * CAPB + base] = jd;
            bcV[(size_t)row * CAPB + base] = 1.0f;     // B diag = 1
            base++;
        }
        bcN[row] = base < CAPB ? base : CAPB;
    }
}

// Sparse x sparse augment (level 0->1 only, nz ~16): dense LDS row via atomicAdd
// (exact integers -> order-independent), diag zero, rowsum -> dinv, compaction.
// FUSED: wave 1 computes g[i,:] = dinv1[i] * (hp[i,:] @ W1) while wave 0 compacts.
__global__ void k_aug_sparse(const int* __restrict__ perm,
                             const int* __restrict__ colsS, const float* __restrict__ valsS,
                             const int* __restrict__ cntS, int CAPS,
                             const int* __restrict__ bcC, const float* __restrict__ bcV,
                             const int* __restrict__ bcN, int CAPB, int kk,
                             int* __restrict__ colsD, float* __restrict__ valsD,
                             int* __restrict__ cntD, float* __restrict__ dinvD, int CAPD,
                             const float* __restrict__ hp, const float* __restrict__ W,
                             float* __restrict__ gOut) {
    __shared__ float srow[1504];
    __shared__ float ssum[4];
    int i = blockIdx.x;
    int pi = perm[i];
    int nzS = cntS[pi];
    for (int t = threadIdx.x; t < 1504; t += blockDim.x) srow[t] = 0.0f;
    __syncthreads();
    int w = threadIdx.x >> 6, lane = threadIdx.x & 63;
    // ee in [0, nzS]; ee == nzS is the implicit diag entry (k=pi, val=1)
    for (int ee = w; ee <= nzS; ee += 4) {
        int k; float kv;
        if (ee == nzS) { k = pi; kv = 1.0f; }
        else {
            k = colsS[(size_t)pi * CAPS + ee];
            if (k == pi) continue;               // original diag replaced by implicit 1
            kv = valsS[(size_t)pi * CAPS + ee];
        }
        int bn = bcN[k];
        const int*   bc = bcC + (size_t)k * CAPB;
        const float* bv = bcV + (size_t)k * CAPB;
        for (int t = lane; t < bn; t += 64)
            atomicAdd(&srow[bc[t]], kv * bv[t]);
    }
    __syncthreads();
    if (threadIdx.x == 0) srow[i] = 0.0f;        // zero output diag
    __syncthreads();
    float psum = 0.0f;
    for (int t = threadIdx.x; t < kk; t += blockDim.x) psum += srow[t];
    for (int off = 32; off; off >>= 1) psum += __shfl_down(psum, off, 64);
    if (lane == 0) ssum[w] = psum;
    __syncthreads();
    if (w == 0) {
        if (lane == 0)
            dinvD[i] = rsqrtf((ssum[0] + ssum[1]) + (ssum[2] + ssum[3]) + 2.0f);
        int base = 0;
        for (int c0 = 0; c0 < kk; c0 += 64) {
            int c = c0 + lane;
            float v = (c < kk) ? srow[c] : 0.0f;
            unsigned long long mb = __ballot(v != 0.0f);
            if (v != 0.0f) {
                int idx = base + __popcll(mb & ((1ull << lane) - 1ull));
                if (idx < CAPD) {
                    colsD[(size_t)i * CAPD + idx] = c;
                    valsD[(size_t)i * CAPD + idx] = v;
                }
            }
            base += __popcll(mb);
        }
        if (lane == 0) cntD[i] = base < CAPD ? base : CAPD;
    } else if (w == 1) {
        // fused xw1: g[i,:] = dinv1[i] * (hp[i,:] @ W)  (IC=OC=64)
        float dv = rsqrtf((ssum[0] + ssum[1]) + (ssum[2] + ssum[3]) + 2.0f);
        const float* hrow = hp + (size_t)i * 64;
        float acc = 0.0f;
        for (int k = 0; k < 64; ++k) acc += hrow[k] * W[k * 64 + lane];
        gOut[(size_t)i * 64 + lane] = dv * acc;
    }
}

// Dense Bcol panel with FUSED zero-fill: block per row, zero the row at full BW,
// sync, then scatter CSR nonzeros (diag forced 1).
__global__ void k_bcol_scatter(const int* __restrict__ cols, const float* __restrict__ vals,
                               const int* __restrict__ cnt, int CAP,
                               const int* __restrict__ selpos, float* __restrict__ Bcol, int ldb) {
    int row = blockIdx.x;
    float4* rowp = (float4*)(Bcol + (size_t)row * ldb);
    float4 z = {0.f, 0.f, 0.f, 0.f};
    for (int q = threadIdx.x; q < (ldb >> 2); q += blockDim.x) rowp[q] = z;
    __syncthreads();
    int nz = cnt[row];
    for (int e = threadIdx.x; e < nz; e += blockDim.x) {
        int c = cols[(size_t)row * CAP + e];
        if (c == row) continue;                 // diag handled below
        int j = selpos[c];
        if (j >= 0) Bcol[(size_t)row * ldb + j] = vals[(size_t)row * CAP + e];
    }
    if (threadIdx.x == 0) {
        int j = selpos[row];
        if (j >= 0) Bcol[(size_t)row * ldb + j] = 1.0f;  // B diag = 1
    }
}

// Level-2 augment, e-split partials: grid (KK2, ESPLIT). Block (192) computes a
// PARTIAL dense row over its nonzero sub-range (8-ILP float4 gather) and stores
// it to T2p[split][i][:] with plain stores (no atomics; deterministic).
// Split 0 carries the implicit-diag term (1 * Bcol[pi][:]).
__global__ void k_aug_part(const int* __restrict__ perm,
                           const int* __restrict__ colsS, const float* __restrict__ valsS,
                           const int* __restrict__ cntS, int CAPS,
                           const float* __restrict__ Bcol, int ldb, int kk,
                           float* __restrict__ T2p) {
    __shared__ int   scol[CAPMAX];
    __shared__ float sval[CAPMAX];
    int i = blockIdx.x, sp = blockIdx.y;
    int pi = perm[i];
    int nz = cntS[pi];
    for (int e = threadIdx.x; e < nz; e += blockDim.x) {
        int c = colsS[(size_t)pi * CAPS + e];
        scol[e] = c;
        sval[e] = (c == pi) ? 0.0f : valsS[(size_t)pi * CAPS + e];  // diag via Bcol[pi] term
    }
    __syncthreads();
    int j0 = threadIdx.x * 4;
    if (j0 >= ldb) return;
    int j4 = j0 >> 2;
    float4 a = {0.f, 0.f, 0.f, 0.f};
    if (sp == 0) a = ((const float4*)(Bcol + (size_t)pi * ldb))[j4];  // 1 * B[pi, perm[j..j+3]]
    float4 acc1 = {0.f, 0.f, 0.f, 0.f};
    int e  = (nz * sp) / ESPLIT;
    int e1 = (nz * (sp + 1)) / ESPLIT;
    for (; e + 8 <= e1; e += 8) {
        float v0 = sval[e],     v1 = sval[e + 1], v2 = sval[e + 2], v3 = sval[e + 3];
        float v4 = sval[e + 4], v5 = sval[e + 5], v6 = sval[e + 6], v7 = sval[e + 7];
        float4 b0 = ((const float4*)(Bcol + (size_t)scol[e]     * ldb))[j4];
        float4 b1 = ((const float4*)(Bcol + (size_t)scol[e + 1] * ldb))[j4];
        float4 b2 = ((const float4*)(Bcol + (size_t)scol[e + 2] * ldb))[j4];
        float4 b3 = ((const float4*)(Bcol + (size_t)scol[e + 3] * ldb))[j4];
        float4 b4 = ((const float4*)(Bcol + (size_t)scol[e + 4] * ldb))[j4];
        float4 b5 = ((const float4*)(Bcol + (size_t)scol[e + 5] * ldb))[j4];
        float4 b6 = ((const float4*)(Bcol + (size_t)scol[e + 6] * ldb))[j4];
        float4 b7 = ((const float4*)(Bcol + (size_t)scol[e + 7] * ldb))[j4];
        a.x += v0 * b0.x + v1 * b1.x + v2 * b2.x + v3 * b3.x;
        a.y += v0 * b0.y + v1 * b1.y + v2 * b2.y + v3 * b3.y;
        a.z += v0 * b0.z + v1 * b1.z + v2 * b2.z + v3 * b3.z;
        a.w += v0 * b0.w + v1 * b1.w + v2 * b2.w + v3 * b3.w;
        acc1.x += v4 * b4.x + v5 * b5.x + v6 * b6.x + v7 * b7.x;
        acc1.y += v4 * b4.y + v5 * b5.y + v6 * b6.y + v7 * b7.y;
        acc1.z += v4 * b4.z + v5 * b5.z + v6 * b6.z + v7 * b7.z;
        acc1.w += v4 * b4.w + v5 * b5.w + v6 * b6.w + v7 * b7.w;
    }
    for (; e < e1; ++e) {
        float v = sval[e];
        float4 b = ((const float4*)(Bcol + (size_t)scol[e] * ldb))[j4];
        a.x += v * b.x; a.y += v * b.y; a.z += v * b.z; a.w += v * b.w;
    }
    a.x += acc1.x; a.y += acc1.y; a.z += acc1.z; a.w += acc1.w;
    *(float4*)(T2p + ((size_t)sp * KK2 + i) * ldb + j0) = a;
}

// Sum ESPLIT partial slices, zero diag, compact to CSR2, rowsum -> dinv2.
// Wave per row (4 rows/block). FUSED: g[row,:] = dinv2[row] * (hp2[row,:] @ W2).
__global__ void k_csr2_build(const float* __restrict__ T2p,
                             int* __restrict__ cols, float* __restrict__ vals,
                             int* __restrict__ cnt, float* __restrict__ dinv,
                             const float* __restrict__ hp2, const float* __restrict__ W2,
                             float* __restrict__ g) {
    int row = blockIdx.x * (blockDim.x >> 6) + (threadIdx.x >> 6);
    int lane = threadIdx.x & 63;
    if (row >= KK2) return;
    const float* r0 = T2p + ((size_t)0 * KK2 + row) * KK2P;
    const float* r1 = T2p + ((size_t)1 * KK2 + row) * KK2P;
    const float* r2 = T2p + ((size_t)2 * KK2 + row) * KK2P;
    const float* r3 = T2p + ((size_t)3 * KK2 + row) * KK2P;
    int base = 0;
    float s = 0.0f;
    for (int c0 = 0; c0 < KK2; c0 += 64) {
        int c = c0 + lane;
        float v = 0.0f;
        if (c < KK2 && c != row) v = (r0[c] + r1[c]) + (r2[c] + r3[c]);
        unsigned long long mb = __ballot(v != 0.0f);
        if (v != 0.0f) {
            int idx = base + __popcll(mb & ((1ull << lane) - 1ull));
            if (idx < CAP2) {
                cols[(size_t)row * CAP2 + idx] = c;
                vals[(size_t)row * CAP2 + idx] = v;
            }
            s += v;
        }
        base += __popcll(mb);
    }
    for (int off = 32; off; off >>= 1) s += __shfl_xor(s, off, 64);  // all-lanes total
    float dv = rsqrtf(s + 2.0f);
    if (lane == 0) {
        cnt[row] = base < CAP2 ? base : CAP2;
        dinv[row] = dv;
    }
    // fused xw2 (IC=OC=64)
    const float* hrow = hp2 + (size_t)row * 64;
    float acc = 0.0f;
    for (int k = 0; k < 64; ++k) acc += hrow[k] * W2[k * 64 + lane];
    g[(size_t)row * 64 + lane] = dv * acc;
}

// ---------------- launch ----------------

extern "C" void kernel_launch(void* const* d_in, const int* in_sizes, int n_in,
                              void* d_out, int out_size, void* d_ws, size_t ws_size,
                              hipStream_t stream) {
    const float* x   = (const float*)d_in[0];
    const int*   ei  = (const int*)d_in[1];
    const float* W0  = (const float*)d_in[2];
    const float* b0  = (const float*)d_in[3];
    const float* W1  = (const float*)d_in[4];
    const float* b1  = (const float*)d_in[5];
    const float* W2  = (const float*)d_in[6];
    const float* b2  = (const float*)d_in[7];
    const float* p1  = (const float*)d_in[8];
    const float* p2  = (const float*)d_in[9];
    const float* Wu0 = (const float*)d_in[10];
    const float* bu0 = (const float*)d_in[11];
    const float* Wu1 = (const float*)d_in[12];
    const float* bu1 = (const float*)d_in[13];
    float* out = (float*)d_out;

    // ---- workspace layout (float units) ----
    float* fw = (float*)d_ws;
    size_t off = 0;
    int*   slots  = (int*)(fw + off); off += (size_t)NN * SLOT;
    int*   cntraw = (int*)(fw + off); off += NN;
    int*   cols0  = (int*)(fw + off); off += (size_t)NN * CAP0;
    float* vals0  = fw + off;         off += (size_t)NN * CAP0;
    int*   cols1  = (int*)(fw + off); off += (size_t)KK1 * CAP1;
    float* vals1  = fw + off;         off += (size_t)KK1 * CAP1;
    int*   cols2  = (int*)(fw + off); off += (size_t)KK2 * CAP2;
    float* vals2  = fw + off;         off += (size_t)KK2 * CAP2;
    int*   bc0C   = (int*)(fw + off); off += (size_t)NN * CAPB0;
    float* bc0V   = fw + off;         off += (size_t)NN * CAPB0;
    int*   bc0N   = (int*)(fw + off); off += NN;
    float* Bcol2  = fw + off;         off += (size_t)KK1 * KK2P;
    float* T2p    = fw + off;         off += (size_t)ESPLIT * KK2 * KK2P;
    int*   cnt0   = (int*)(fw + off); off += NN;
    int*   cnt1   = (int*)(fw + off); off += KK1;
    int*   cnt2   = (int*)(fw + off); off += KK2 + 2;
    float* g      = fw + off; off += (size_t)NN * HIDC;
    float* res0   = fw + off; off += (size_t)NN * HIDC;
    float* res1   = fw + off; off += (size_t)KK1 * HIDC;
    float* hp     = fw + off; off += (size_t)KK1 * HIDC;
    float* hp2    = fw + off; off += (size_t)KK2 * HIDC;
    float* x2     = fw + off; off += (size_t)KK2 * HIDC;
    float* xu     = fw + off; off += (size_t)KK1 * HIDC;
    float* sc1    = fw + off; off += NN;
    float* sc2    = fw + off; off += KK1;
    float* dinv0  = fw + off; off += NN;
    float* dinv1  = fw + off; off += KK1;
    float* dinv2  = fw + off; off += KK2 + 2;
    int* perm1    = (int*)(fw + off); off += KK1;
    int* perm2    = (int*)(fw + off); off += KK2 + 2;
    int* selpos1  = (int*)(fw + off); off += NN;
    int* selpos2  = (int*)(fw + off); off += KK1;
    if (ws_size < off * sizeof(float)) return;

    dim3 b64(64), b192(192), b256(256);

    // ---- CSR0 + dinv0 + g0 directly from edge list
    k_zero_i32<<<dim3((NN + 255) / 256), b256, 0, stream>>>(cntraw, NN);
    k_edge_slots<<<dim3((EE + 255) / 256), b256, 0, stream>>>(ei, cntraw, slots);
    k_csr0_sort<<<dim3(NN / 4), b256, 0, stream>>>(cntraw, slots, cols0, vals0, cnt0, dinv0,
                                                   x, W0, g);

    // ---- GCN0 -> res0 (+score sc1)
    k_gcn_agg_csr<<<dim3(NN), b256, 0, stream>>>(cols0, vals0, cnt0, CAP0, g, dinv0, b0, res0, NN, 64, 1, p1, sc1);

    // ---- pool 1 (topk + pool fused), sparse augment (+fused xw1) -> CSR1, dinv1, g1
    k_topk<<<dim3(NN), b256, 0, stream>>>(sc1, res0, NN, KK1, perm1, selpos1, hp);
    k_bcolcsr<<<dim3(NN / 4), b256, 0, stream>>>(cols0, vals0, cnt0, CAP0, selpos1, NN, bc0C, bc0V, bc0N, CAPB0);
    k_aug_sparse<<<dim3(KK1), b256, 0, stream>>>(perm1, cols0, vals0, cnt0, CAP0,
                                                 bc0C, bc0V, bc0N, CAPB0, KK1,
                                                 cols1, vals1, cnt1, dinv1, CAP1,
                                                 hp, W1, g);

    // ---- GCN1 -> res1 (+score sc2)
    k_gcn_agg_csr<<<dim3(KK1), b256, 0, stream>>>(cols1, vals1, cnt1, CAP1, g, dinv1, b1, res1, KK1, 64, 1, p2, sc2);

    // ---- pool 2, e-split dense-gather augment -> CSR2, dinv2, g2 (fused xw2)
    k_topk<<<dim3(KK1), b256, 0, stream>>>(sc2, res1, KK1, KK2, perm2, selpos2, hp2);
    k_bcol_scatter<<<dim3(KK1), b256, 0, stream>>>(cols1, vals1, cnt1, CAP1, selpos2, Bcol2, KK2P);
    k_aug_part<<<dim3(KK2, ESPLIT), b192, 0, stream>>>(perm2, cols1, vals1, cnt1, CAP1,
                                                       Bcol2, KK2P, KK2, T2p);
    k_csr2_build<<<dim3((KK2 + 3) / 4), b256, 0, stream>>>(T2p, cols2, vals2, cnt2, dinv2,
                                                           hp2, W2, g);

    // ---- GCN2 -> x2
    k_gcn_agg_csr<<<dim3(KK2), b256, 0, stream>>>(cols2, vals2, cnt2, CAP2, g, dinv2, b2, x2, KK2, 64, 1, nullptr, nullptr);

    // ---- up to level 1: h = res1 + up(x2 via selpos2); GCN(Wu0) -> xu
    k_xw_scale<<<dim3(KK1), b64, 0, stream>>>(res1, x2, selpos2, Wu0, dinv1, g, KK1, 64, 64);
    k_gcn_agg_csr<<<dim3(KK1), b256, 0, stream>>>(cols1, vals1, cnt1, CAP1, g, dinv1, bu0, xu, KK1, 64, 1, nullptr, nullptr);

    // ---- up to level 0: h = res0 + up(xu via selpos1); GCN(Wu1) -> out (no tanh)
    k_xw_scale<<<dim3(NN), b64, 0, stream>>>(res0, xu, selpos1, Wu1, dinv0, g, NN, 64, 16);
    k_gcn_agg_csr<<<dim3(NN), b256, 0, stream>>>(cols0, vals0, cnt0, CAP0, g, dinv0, bu1, out, NN, 16, 0, nullptr, nullptr);
}